// Round 23
// baseline (215.750 us; speedup 1.0000x reference)
//
#include <hip/hip_runtime.h>
#include <hip/hip_fp16.h>

#define NF 64
#define KEXP 50
#define TBL 16384           // nearest-neighbor fp16 table (2MB)
#define CUTF 5.0f
#define LOG2C 0.6931471805599453f
#define GRP 32              // nodes per group (agg block granule)
#define GSH 5               // log2(GRP)
#define NSC 256             // superchunks (sort blocks)
#define GMAX 4096           // max node-groups (LDS histogram bound)
#define SCAP 768            // max records per group (mean 512, +11 sigma)
#define RPT (SCAP / 256)    // records per thread staged in registers

typedef unsigned long long ull;
typedef _Float16 f16x8 __attribute__((ext_vector_type(8)));
typedef float f32x4 __attribute__((ext_vector_type(4)));

__device__ __forceinline__ float sspf(float x) {
    // fast softplus(x) - log2
    return fmaxf(x, 0.0f) + __logf(1.0f + __expf(-fabsf(x))) - LOG2C;
}

// load 8 consecutive fp32 from row-major w[f][k0..k0+7] as f16x8 (MFMA B-frag)
__device__ __forceinline__ f16x8 load_wfrag(const float* __restrict__ w, int f, int k0) {
    const float4 q0 = *(const float4*)(w + (size_t)f * NF + k0);
    const float4 q1 = *(const float4*)(w + (size_t)f * NF + k0 + 4);
    f16x8 r;
    r[0] = (_Float16)q0.x; r[1] = (_Float16)q0.y; r[2] = (_Float16)q0.z; r[3] = (_Float16)q0.w;
    r[4] = (_Float16)q1.x; r[5] = (_Float16)q1.y; r[6] = (_Float16)q1.z; r[7] = (_Float16)q1.w;
    return r;
}

__device__ __forceinline__ f16x8 load_afrag_f32(const float* p) {
    const float4 q0 = *(const float4*)(p);
    const float4 q1 = *(const float4*)(p + 4);
    f16x8 r;
    r[0] = (_Float16)q0.x; r[1] = (_Float16)q0.y; r[2] = (_Float16)q0.z; r[3] = (_Float16)q0.w;
    r[4] = (_Float16)q1.x; r[5] = (_Float16)q1.y; r[6] = (_Float16)q1.z; r[7] = (_Float16)q1.w;
    return r;
}

// ---------------------------------------------------------------------------
// table build (standalone; register-fat by design): 256 blocks x 256 thr.
// ---------------------------------------------------------------------------
__global__ void __launch_bounds__(256) build_tabnn_k(
    const float* __restrict__ f_w1, const float* __restrict__ f_b1,
    const float* __restrict__ f_w2, const float* __restrict__ f_b2,
    __half* __restrict__ tabnn) {
    const int tid = threadIdx.x;
    const int lane = tid & 63;
    const int wid = tid >> 6;
    float w1r[KEXP], w2r[NF];
    for (int k = 0; k < KEXP; ++k) w1r[k] = f_w1[lane * KEXP + k];
    for (int k = 0; k < NF; ++k)  w2r[k] = f_w2[lane * NF + k];
    const float b1 = f_b1[lane], b2 = f_b2[lane];
    const float delta = CUTF / (float)(KEXP - 1);
    const float coeff = -0.5f / (delta * delta);
    const float dstep = CUTF / (float)(TBL - 1);
    for (int tt = 0; tt < 16; ++tt) {
        const int t = blockIdx.x * 64 + wid * 16 + tt;
        const float d = (float)t * dstep;
        float rbfv = 0.f;
        if (lane < KEXP) {
            const float dd = d - (float)lane * delta;
            rbfv = __expf(coeff * dd * dd);
        }
        float t1 = b1;
        for (int k = 0; k < KEXP; ++k) t1 = fmaf(__shfl(rbfv, k), w1r[k], t1);
        const float sv = sspf(t1);
        float t2 = b2;
        for (int k = 0; k < NF; ++k) t2 = fmaf(__shfl(sv, k), w2r[k], t2);
        tabnn[(size_t)t * NF + lane] = __float2half(t2);
    }
}

// ---------------------------------------------------------------------------
// front_k: fused [hist | prep] — both register-light.
// ---------------------------------------------------------------------------
__global__ void __launch_bounds__(256) front_k(
    const int* __restrict__ nbr_dst, int n_edges, int ngroups, int chk,
    unsigned* __restrict__ cnt,
    const float* __restrict__ x, const float* __restrict__ w,
    const float* __restrict__ b, __half* __restrict__ h16, int n_nodes)
{
    __shared__ __align__(16) char smem[GMAX * 4];   // 16KB union
    const int blk = blockIdx.x;
    const int tid = threadIdx.x;
    const int lane = tid & 63;
    const int wid = tid >> 6;

    if (blk < NSC) {
        unsigned* cnt_s = (unsigned*)smem;
        const int c = blk;
        const int e0 = c * chk;
        const int e1 = min(e0 + chk, n_edges);
        const int m = max(e1 - e0, 0);
        for (int g = tid; g < ngroups; g += 256) cnt_s[g] = 0u;
        __syncthreads();
        for (int i = tid; i < m; i += 256)
            atomicAdd(&cnt_s[(unsigned)nbr_dst[e0 + i] >> GSH], 1u);
        __syncthreads();
        const size_t ob = (size_t)c * ngroups;
        for (int g = tid; g < ngroups; g += 256) cnt[ob + g] = cnt_s[g];
    } else {
        _Float16 (*stile)[16][72] = (_Float16(*)[16][72])smem;
        const int col = lane & 15;
        const int quad = lane >> 4;
        f16x8 bw[4][2];
        float bv[4];
        #pragma unroll
        for (int t = 0; t < 4; ++t) {
            #pragma unroll
            for (int kb = 0; kb < 2; ++kb)
                bw[t][kb] = load_wfrag(w, 16 * t + col, kb * 32 + quad * 8);
            bv[t] = b[16 * t + col];
        }
        const int pb = blk - NSC;
        const int pgrid = gridDim.x - NSC;
        const int ntiles = (n_nodes + 15) >> 4;
        for (int tile = pb * 4 + wid; tile < ntiles; tile += pgrid * 4) {
            const int n0 = tile << 4;
            const int nr = min(n0 + col, n_nodes - 1);
            f16x8 a[2];
            #pragma unroll
            for (int kb = 0; kb < 2; ++kb)
                a[kb] = load_afrag_f32(x + (size_t)nr * NF + kb * 32 + quad * 8);
            f32x4 acc[4];
            #pragma unroll
            for (int t = 0; t < 4; ++t) acc[t] = (f32x4){bv[t], bv[t], bv[t], bv[t]};
            #pragma unroll
            for (int t = 0; t < 4; ++t)
                #pragma unroll
                for (int kb = 0; kb < 2; ++kb)
                    acc[t] = __builtin_amdgcn_mfma_f32_16x16x32_f16(a[kb], bw[t][kb], acc[t], 0, 0, 0);
            #pragma unroll
            for (int t = 0; t < 4; ++t)
                #pragma unroll
                for (int r = 0; r < 4; ++r)
                    stile[wid][quad * 4 + r][16 * t + col] = (_Float16)acc[t][r];
            __threadfence_block();
            #pragma unroll
            for (int it = 0; it < 2; ++it) {
                const int chunk = it * 64 + lane;
                const int row = chunk >> 3;
                const int off = (chunk & 7) * 8;
                const int n = n0 + row;
                if (n < n_nodes)
                    *(uint4*)(h16 + (size_t)n * NF + off) = *(const uint4*)&stile[wid][row][off];
            }
            __threadfence_block();
        }
    }
}

// ---------------------------------------------------------------------------
// colscan: per group g, exclusive scan of cnt[c][g] along c (NSC=256, 4/lane)
// ---------------------------------------------------------------------------
__global__ void __launch_bounds__(64) colscan_k(const unsigned* __restrict__ cnt,
                                                unsigned* __restrict__ colpre,
                                                unsigned* __restrict__ tot, int ngroups) {
    const int g = blockIdx.x;
    const int lane = threadIdx.x;
    unsigned v[4];
    unsigned s = 0u;
    #pragma unroll
    for (int j = 0; j < 4; ++j) {
        v[j] = cnt[(size_t)(4 * lane + j) * ngroups + g];
        s += v[j];
    }
    unsigned run = s;
    #pragma unroll
    for (int d = 1; d < 64; d <<= 1) {
        const unsigned t = __shfl_up(run, d, 64);
        if (lane >= d) run += t;
    }
    unsigned pre = run - s;
    #pragma unroll
    for (int j = 0; j < 4; ++j) {
        colpre[(size_t)(4 * lane + j) * ngroups + g] = pre;
        pre += v[j];
    }
    if (lane == 63) tot[g] = run;
}

// ---------------------------------------------------------------------------
// base: exclusive scan over group totals -> gbase[0..ngroups]
// ---------------------------------------------------------------------------
__global__ void __launch_bounds__(64) base_k(const unsigned* __restrict__ tot,
                                             unsigned* __restrict__ gbase, int ngroups) {
    const int lane = threadIdx.x;
    unsigned carry = 0u;
    for (int base = 0; base < ngroups; base += 64) {
        const int g = base + lane;
        const unsigned v = (g < ngroups) ? tot[g] : 0u;
        unsigned run = v;
        #pragma unroll
        for (int d = 1; d < 64; d <<= 1) {
            const unsigned t = __shfl_up(run, d, 64);
            if (lane >= d) run += t;
        }
        if (g < ngroups) gbase[g] = carry + run - v;
        carry += (unsigned)__shfl((int)run, 63, 64);
    }
    if (lane == 0) gbase[ngroups] = carry;
}

// ---------------------------------------------------------------------------
// scatter2: write records to FINAL globally-sorted-by-group positions.
// rec: lo = i0<<7 (tab row byte offset) ; hi = (src<<7)|dstrow(5b)
// ---------------------------------------------------------------------------
__global__ void __launch_bounds__(1024) scatter2_k(const int* __restrict__ nbr,
                                                   const float* __restrict__ dist,
                                                   int n_edges, int ngroups, int chk,
                                                   const unsigned* __restrict__ colpre,
                                                   const unsigned* __restrict__ gbase,
                                                   ull* __restrict__ payload) {
    __shared__ unsigned cur_s[GMAX];
    const int tid = threadIdx.x;
    const int c = blockIdx.x;
    const int e0 = c * chk;
    const int e1 = min(e0 + chk, n_edges);
    const int m = max(e1 - e0, 0);
    const size_t ob = (size_t)c * ngroups;
    for (int g = tid; g < ngroups; g += 1024) cur_s[g] = gbase[g] + colpre[ob + g];
    __syncthreads();
    const float scale = (float)(TBL - 1) / CUTF;
    for (int i = tid; i < m; i += 1024) {
        const int e = e0 + i;
        const unsigned dst = (unsigned)nbr[n_edges + e];
        const unsigned src = (unsigned)nbr[e];
        const float xx = dist[e] * scale + 0.5f;
        int i0 = (int)xx;
        i0 = max(0, min(i0, TBL - 1));
        const ull rec = (ull)((unsigned)i0 << 7) |
                        ((ull)((src << 7) | (dst & (GRP - 1u))) << 32);
        const unsigned pos = atomicAdd(&cur_s[dst >> GSH], 1u);
        payload[pos] = rec;
    }
}

// ---------------------------------------------------------------------------
// agg+mlp fused: block = 32-node group. Gather phases identical to r22's
// agg_k but accumulate into LDS aggf; inline overflow tail; then waves 0,1
// run the output MLP (weights loaded AFTER gather to keep gather-phase VGPR
// low) and write final out. No global agg buffer, no oflow2/out_mlp launches.
// ---------------------------------------------------------------------------
__global__ void __launch_bounds__(256) agg_mlp_k(
    const ull* __restrict__ payload, const unsigned* __restrict__ gbase,
    const __half* __restrict__ h16, const __half* __restrict__ tabnn,
    const float* __restrict__ w1, const float* __restrict__ b1,
    const float* __restrict__ w2, const float* __restrict__ b2,
    float* __restrict__ out, int n_nodes)
{
    __shared__ ull sorted_s[SCAP];
    __shared__ float aggf[GRP][NF + 4];
    __shared__ _Float16 hs[2][16][72];
    __shared__ unsigned cnt_s[GRP];
    __shared__ unsigned base_s[GRP];
    __shared__ unsigned cur_s[GRP];
    const int tid = threadIdx.x;
    const int lane = tid & 63;
    const int wid = tid >> 6;   // 0..3
    const int g = blockIdx.x;
    const unsigned beg = gbase[g];
    const unsigned end = gbase[g + 1];
    const unsigned tot = min(end - beg, (unsigned)SCAP);

    if (tid < GRP) cnt_s[tid] = 0u;
    __syncthreads();
    // Phase A: stage records in registers (coalesced), count rows
    ull rec[RPT];
    #pragma unroll
    for (int k = 0; k < RPT; ++k) {
        const unsigned i = (unsigned)(k * 256) + tid;
        rec[k] = 0ull;
        if (i < tot) {
            rec[k] = payload[beg + i];
            atomicAdd(&cnt_s[(unsigned)(rec[k] >> 32) & (GRP - 1u)], 1u);
        }
    }
    __syncthreads();
    // exclusive scan over GRP row counts
    if (tid < GRP) {
        const unsigned c = cnt_s[tid];
        unsigned run = c;
        #pragma unroll
        for (int d = 1; d < GRP; d <<= 1) {
            const unsigned t = __shfl_up(run, d, 64);
            if (tid >= d) run += t;
        }
        base_s[tid] = run - c;
        cur_s[tid]  = run - c;
    }
    __syncthreads();
    // Phase B: place by row (registers -> LDS)
    #pragma unroll
    for (int k = 0; k < RPT; ++k) {
        const unsigned i = (unsigned)(k * 256) + tid;
        if (i < tot) {
            const unsigned pos = atomicAdd(&cur_s[(unsigned)(rec[k] >> 32) & (GRP - 1u)], 1u);
            sorted_s[pos] = rec[k];
        }
    }
    __syncthreads();
    // Phase C: gather-accumulate into LDS aggf
    const char* tabB = (const char*)tabnn + (lane << 1);
    const char* hB   = (const char*)h16 + (lane << 1);
    auto ev = [&](ull r) -> float {
        const unsigned lo = (unsigned)r;          // tab row byte offset
        const unsigned hi = (unsigned)(r >> 32);
        const float tv = __half2float(*(const __half*)(tabB + lo));
        const float hv = __half2float(*(const __half*)(hB + (hi & 0xFFFFFF80u)));
        return tv * hv;
    };
    for (int rr = 0; rr < GRP / 4; ++rr) {
        const int r = wid * (GRP / 4) + rr;
        unsigned i = base_s[r];
        const unsigned e = cur_s[r];
        float acc0 = 0.f, acc1 = 0.f;
        for (; i + 16u <= e; i += 16u) {
            ull rv[16];
            #pragma unroll
            for (int j = 0; j < 16; ++j) rv[j] = sorted_s[i + j];
            float p[16];
            #pragma unroll
            for (int j = 0; j < 16; ++j) p[j] = ev(rv[j]);
            acc0 += ((p[0] + p[1]) + (p[2] + p[3])) + ((p[4] + p[5]) + (p[6] + p[7]));
            acc1 += ((p[8] + p[9]) + (p[10] + p[11])) + ((p[12] + p[13]) + (p[14] + p[15]));
        }
        for (; i + 4u <= e; i += 4u) {
            const ull r0 = sorted_s[i];
            const ull r1 = sorted_s[i + 1];
            const ull r2 = sorted_s[i + 2];
            const ull r3 = sorted_s[i + 3];
            acc0 += ev(r0) + ev(r1);
            acc1 += ev(r2) + ev(r3);
        }
        for (; i < e; ++i) acc0 += ev(sorted_s[i]);
        aggf[r][lane] = acc0 + acc1;
    }
    __syncthreads();
    // inline overflow tail (records beyond SCAP; normally zero)
    if (end - beg > (unsigned)SCAP) {
        for (unsigned i = (unsigned)SCAP + (unsigned)wid; i < end - beg; i += 4u) {
            const ull r = payload[beg + i];
            const unsigned row = (unsigned)(r >> 32) & (GRP - 1u);
            atomicAdd(&aggf[row][lane], ev(r));
        }
        __syncthreads();
    }
    // MLP: waves 0,1 each handle one 16-node tile (weights loaded here so
    // their VGPR liveness does not overlap the gather phases)
    if (wid < 2) {
        const int col = lane & 15;
        const int quad = lane >> 4;
        f16x8 bw1r[4][2], bw2r[4][2];
        float b1v[4], b2v[4];
        #pragma unroll
        for (int t = 0; t < 4; ++t) {
            #pragma unroll
            for (int kb = 0; kb < 2; ++kb) {
                bw1r[t][kb] = load_wfrag(w1, 16 * t + col, kb * 32 + quad * 8);
                bw2r[t][kb] = load_wfrag(w2, 16 * t + col, kb * 32 + quad * 8);
            }
            b1v[t] = b1[16 * t + col];
            b2v[t] = b2[16 * t + col];
        }
        f16x8 a[2];
        #pragma unroll
        for (int kb = 0; kb < 2; ++kb)
            a[kb] = load_afrag_f32(&aggf[wid * 16 + col][kb * 32 + quad * 8]);
        f32x4 acc[4];
        #pragma unroll
        for (int t = 0; t < 4; ++t) acc[t] = (f32x4){b1v[t], b1v[t], b1v[t], b1v[t]};
        #pragma unroll
        for (int t = 0; t < 4; ++t)
            #pragma unroll
            for (int kb = 0; kb < 2; ++kb)
                acc[t] = __builtin_amdgcn_mfma_f32_16x16x32_f16(a[kb], bw1r[t][kb], acc[t], 0, 0, 0);
        #pragma unroll
        for (int t = 0; t < 4; ++t)
            #pragma unroll
            for (int r = 0; r < 4; ++r)
                hs[wid][quad * 4 + r][16 * t + col] = (_Float16)sspf(acc[t][r]);
        __threadfence_block();
        f16x8 a2[2];
        #pragma unroll
        for (int kb = 0; kb < 2; ++kb)
            a2[kb] = *(const f16x8*)&hs[wid][col][kb * 32 + quad * 8];
        f32x4 acc2[4];
        #pragma unroll
        for (int t = 0; t < 4; ++t) acc2[t] = (f32x4){b2v[t], b2v[t], b2v[t], b2v[t]};
        #pragma unroll
        for (int t = 0; t < 4; ++t)
            #pragma unroll
            for (int kb = 0; kb < 2; ++kb)
                acc2[t] = __builtin_amdgcn_mfma_f32_16x16x32_f16(a2[kb], bw2r[t][kb], acc2[t], 0, 0, 0);
        const int n0 = g * GRP + wid * 16;
        #pragma unroll
        for (int t = 0; t < 4; ++t)
            #pragma unroll
            for (int r = 0; r < 4; ++r) {
                const int n = n0 + quad * 4 + r;
                if (n < n_nodes) out[(size_t)n * NF + 16 * t + col] = acc2[t][r];
            }
    }
}

// ---------------------------------------------------------------------------
// fallback edge kernel (direct atomic scatter-add) — used only if ws too small
// ---------------------------------------------------------------------------
__global__ void edge_k(const int* __restrict__ nbr, const float* __restrict__ dist,
                       const __half* __restrict__ h16, const __half* __restrict__ tabnn,
                       float* __restrict__ agg, int n_edges) {
    const int tid = threadIdx.x;
    const int lane = tid & 63;
    const int nwaves = (gridDim.x * blockDim.x) >> 6;
    const int gw = (blockIdx.x * blockDim.x + tid) >> 6;
    const float scale = (float)(TBL - 1) / CUTF;
    const int nbatch = n_edges >> 6;
    for (int bb = gw; bb < nbatch; bb += nwaves) {
        const int e0 = bb << 6;
        int src = nbr[e0 + lane];
        int dst = nbr[n_edges + e0 + lane];
        float d = dist[e0 + lane];
        float xx = d * scale + 0.5f;
        int i0 = (int)xx;
        i0 = max(0, min(i0, TBL - 1));
        #pragma unroll 4
        for (int j = 0; j < 64; ++j) {
            const int sj = __shfl(src, j);
            const int dj = __shfl(dst, j);
            const int ij = __shfl(i0, j);
            const float tv = __half2float(tabnn[(size_t)ij * NF + lane]);
            const float hv = __half2float(h16[(size_t)sj * NF + lane]);
            atomicAdd(agg + (size_t)dj * NF + lane, tv * hv);
        }
    }
    if (gw == 0) {
        for (int e = nbatch << 6; e < n_edges; ++e) {
            const int sj = nbr[e];
            const int dj = nbr[n_edges + e];
            const float d = dist[e];
            float xx = d * scale + 0.5f;
            int ij = (int)xx;
            ij = max(0, min(ij, TBL - 1));
            const float tv = __half2float(tabnn[(size_t)ij * NF + lane]);
            const float hv = __half2float(h16[(size_t)sj * NF + lane]);
            atomicAdd(agg + (size_t)dj * NF + lane, tv * hv);
        }
    }
}

// ---------------------------------------------------------------------------
// out_mlp (MFMA) — fallback path only
// ---------------------------------------------------------------------------
__global__ void __launch_bounds__(256) out_mlp_k(const float* __restrict__ agg,
                                                 const float* __restrict__ w1,
                                                 const float* __restrict__ b1,
                                                 const float* __restrict__ w2,
                                                 const float* __restrict__ b2,
                                                 float* __restrict__ out, int n_nodes) {
    __shared__ _Float16 stile[4][16][72];
    const int tid = threadIdx.x;
    const int lane = tid & 63;
    const int wid = tid >> 6;
    const int col = lane & 15;
    const int quad = lane >> 4;

    f16x8 bw1[4][2], bw2[4][2];
    float b1v[4], b2v[4];
    #pragma unroll
    for (int t = 0; t < 4; ++t) {
        #pragma unroll
        for (int kb = 0; kb < 2; ++kb) {
            bw1[t][kb] = load_wfrag(w1, 16 * t + col, kb * 32 + quad * 8);
            bw2[t][kb] = load_wfrag(w2, 16 * t + col, kb * 32 + quad * 8);
        }
        b1v[t] = b1[16 * t + col];
        b2v[t] = b2[16 * t + col];
    }

    const int ntiles = (n_nodes + 15) >> 4;
    for (int tile = blockIdx.x * 4 + wid; tile < ntiles; tile += gridDim.x * 4) {
        const int n0 = tile << 4;
        const int nr = min(n0 + col, n_nodes - 1);
        f16x8 a[2];
        #pragma unroll
        for (int kb = 0; kb < 2; ++kb)
            a[kb] = load_afrag_f32(agg + (size_t)nr * NF + kb * 32 + quad * 8);
        f32x4 acc[4];
        #pragma unroll
        for (int t = 0; t < 4; ++t) acc[t] = (f32x4){b1v[t], b1v[t], b1v[t], b1v[t]};
        #pragma unroll
        for (int t = 0; t < 4; ++t)
            #pragma unroll
            for (int kb = 0; kb < 2; ++kb)
                acc[t] = __builtin_amdgcn_mfma_f32_16x16x32_f16(a[kb], bw1[t][kb], acc[t], 0, 0, 0);
        #pragma unroll
        for (int t = 0; t < 4; ++t)
            #pragma unroll
            for (int r = 0; r < 4; ++r)
                stile[wid][quad * 4 + r][16 * t + col] = (_Float16)sspf(acc[t][r]);
        __threadfence_block();
        f16x8 a2[2];
        #pragma unroll
        for (int kb = 0; kb < 2; ++kb)
            a2[kb] = *(const f16x8*)&stile[wid][col][kb * 32 + quad * 8];
        f32x4 acc2[4];
        #pragma unroll
        for (int t = 0; t < 4; ++t) acc2[t] = (f32x4){b2v[t], b2v[t], b2v[t], b2v[t]};
        #pragma unroll
        for (int t = 0; t < 4; ++t)
            #pragma unroll
            for (int kb = 0; kb < 2; ++kb)
                acc2[t] = __builtin_amdgcn_mfma_f32_16x16x32_f16(a2[kb], bw2[t][kb], acc2[t], 0, 0, 0);
        #pragma unroll
        for (int t = 0; t < 4; ++t)
            #pragma unroll
            for (int r = 0; r < 4; ++r) {
                const int n = n0 + quad * 4 + r;
                if (n < n_nodes) out[(size_t)n * NF + 16 * t + col] = acc2[t][r];
            }
        __threadfence_block();
    }
}

extern "C" void kernel_launch(void* const* d_in, const int* in_sizes, int n_in,
                              void* d_out, int out_size, void* d_ws, size_t ws_size,
                              hipStream_t stream) {
    const int*   nbr   = (const int*)d_in[0];
    const float* dist  = (const float*)d_in[1];
    const float* x     = (const float*)d_in[2];
    const float* lin_w = (const float*)d_in[3];
    const float* lin_b = (const float*)d_in[4];
    const float* f_w1  = (const float*)d_in[5];
    const float* f_b1  = (const float*)d_in[6];
    const float* f_w2  = (const float*)d_in[7];
    const float* f_b2  = (const float*)d_in[8];
    const float* m_w1  = (const float*)d_in[9];
    const float* m_b1  = (const float*)d_in[10];
    const float* m_w2  = (const float*)d_in[11];
    const float* m_b2  = (const float*)d_in[12];

    const int n_edges = in_sizes[1];
    const int n_nodes = in_sizes[2] / NF;
    const int ngroups = (n_nodes + GRP - 1) / GRP;
    const int chk     = (n_edges + NSC - 1) / NSC;
    const int ntiles  = (n_nodes + 15) / 16;
    const int mlp_blk = (ntiles + 3) / 4;

    float* out = (float*)d_out;

    // workspace: h16 | tabnn | cnt | colpre | tot | gbase | payload
    char* ws = (char*)d_ws;
    size_t off = 0;
    auto alloc = [&](size_t bytes) { char* p = ws + off; off = (off + bytes + 255) & ~(size_t)255; return p; };
    __half*   h16     = (__half*)alloc((size_t)n_nodes * NF * sizeof(__half));
    __half*   tabnn   = (__half*)alloc((size_t)TBL * NF * sizeof(__half));
    unsigned* cnt     = (unsigned*)alloc((size_t)NSC * ngroups * sizeof(unsigned));
    unsigned* colpre  = (unsigned*)alloc((size_t)NSC * ngroups * sizeof(unsigned));
    unsigned* tot     = (unsigned*)alloc((size_t)ngroups * sizeof(unsigned));
    unsigned* gbase   = (unsigned*)alloc((size_t)(ngroups + 1) * sizeof(unsigned));
    ull*      payload = (ull*)alloc((size_t)NSC * chk * sizeof(ull));
    const bool sort_path = (off <= ws_size) && (ngroups <= GMAX) && (n_nodes <= (1 << 17));

    build_tabnn_k<<<TBL / 64, 256, 0, stream>>>(f_w1, f_b1, f_w2, f_b2, tabnn);
    // fused front end: hist + prep (both register-light)
    front_k<<<NSC + mlp_blk, 256, 0, stream>>>(
        nbr + n_edges, n_edges, ngroups, chk, cnt,
        x, lin_w, lin_b, h16, n_nodes);

    if (sort_path) {
        colscan_k<<<ngroups, 64, 0, stream>>>(cnt, colpre, tot, ngroups);
        base_k<<<1, 64, 0, stream>>>(tot, gbase, ngroups);
        scatter2_k<<<NSC, 1024, 0, stream>>>(nbr, dist, n_edges, ngroups, chk,
                                             colpre, gbase, payload);
        agg_mlp_k<<<ngroups, 256, 0, stream>>>(payload, gbase, h16, tabnn,
                                               m_w1, m_b1, m_w2, m_b2, out, n_nodes);
    } else {
        float* agg = out;
        hipMemsetAsync(agg, 0, (size_t)n_nodes * NF * sizeof(float), stream);
        edge_k<<<2048, 256, 0, stream>>>(nbr, dist, h16, tabnn, agg, n_edges);
        out_mlp_k<<<mlp_blk, 256, 0, stream>>>(agg, m_w1, m_b1, m_w2, m_b2, out, n_nodes);
    }
}

// Round 24
// 193.162 us; speedup vs baseline: 1.1169x; 1.1169x over previous
//
#include <hip/hip_runtime.h>
#include <hip/hip_fp16.h>

#define NF 64
#define KEXP 50
#define TBL 16384           // nearest-neighbor fp16 table (2MB)
#define CUTF 5.0f
#define LOG2C 0.6931471805599453f
#define GRP 32              // nodes per group (agg block granule)
#define GSH 5               // log2(GRP)
#define NSC 256             // superchunks (sort blocks)
#define GMAX 4096           // max node-groups (LDS histogram bound)
#define SCAP 768            // max records per group (mean 512, +11 sigma)
#define RPT (SCAP / 256)    // records per thread staged in registers

typedef unsigned long long ull;
typedef _Float16 f16x8 __attribute__((ext_vector_type(8)));
typedef float f32x4 __attribute__((ext_vector_type(4)));

__device__ __forceinline__ float sspf(float x) {
    // fast softplus(x) - log2
    return fmaxf(x, 0.0f) + __logf(1.0f + __expf(-fabsf(x))) - LOG2C;
}

// load 8 consecutive fp32 from row-major w[f][k0..k0+7] as f16x8 (MFMA B-frag)
__device__ __forceinline__ f16x8 load_wfrag(const float* __restrict__ w, int f, int k0) {
    const float4 q0 = *(const float4*)(w + (size_t)f * NF + k0);
    const float4 q1 = *(const float4*)(w + (size_t)f * NF + k0 + 4);
    f16x8 r;
    r[0] = (_Float16)q0.x; r[1] = (_Float16)q0.y; r[2] = (_Float16)q0.z; r[3] = (_Float16)q0.w;
    r[4] = (_Float16)q1.x; r[5] = (_Float16)q1.y; r[6] = (_Float16)q1.z; r[7] = (_Float16)q1.w;
    return r;
}

__device__ __forceinline__ f16x8 load_afrag_f32(const float* __restrict__ p) {
    const float4 q0 = *(const float4*)(p);
    const float4 q1 = *(const float4*)(p + 4);
    f16x8 r;
    r[0] = (_Float16)q0.x; r[1] = (_Float16)q0.y; r[2] = (_Float16)q0.z; r[3] = (_Float16)q0.w;
    r[4] = (_Float16)q1.x; r[5] = (_Float16)q1.y; r[6] = (_Float16)q1.z; r[7] = (_Float16)q1.w;
    return r;
}

// ---------------------------------------------------------------------------
// table build (standalone; register-fat by design): 256 blocks x 256 thr.
// ---------------------------------------------------------------------------
__global__ void __launch_bounds__(256) build_tabnn_k(
    const float* __restrict__ f_w1, const float* __restrict__ f_b1,
    const float* __restrict__ f_w2, const float* __restrict__ f_b2,
    __half* __restrict__ tabnn) {
    const int tid = threadIdx.x;
    const int lane = tid & 63;
    const int wid = tid >> 6;
    float w1r[KEXP], w2r[NF];
    for (int k = 0; k < KEXP; ++k) w1r[k] = f_w1[lane * KEXP + k];
    for (int k = 0; k < NF; ++k)  w2r[k] = f_w2[lane * NF + k];
    const float b1 = f_b1[lane], b2 = f_b2[lane];
    const float delta = CUTF / (float)(KEXP - 1);
    const float coeff = -0.5f / (delta * delta);
    const float dstep = CUTF / (float)(TBL - 1);
    for (int tt = 0; tt < 16; ++tt) {
        const int t = blockIdx.x * 64 + wid * 16 + tt;
        const float d = (float)t * dstep;
        float rbfv = 0.f;
        if (lane < KEXP) {
            const float dd = d - (float)lane * delta;
            rbfv = __expf(coeff * dd * dd);
        }
        float t1 = b1;
        for (int k = 0; k < KEXP; ++k) t1 = fmaf(__shfl(rbfv, k), w1r[k], t1);
        const float sv = sspf(t1);
        float t2 = b2;
        for (int k = 0; k < NF; ++k) t2 = fmaf(__shfl(sv, k), w2r[k], t2);
        tabnn[(size_t)t * NF + lane] = __float2half(t2);
    }
}

// ---------------------------------------------------------------------------
// front_k: fused [hist | prep] — both register-light.
// ---------------------------------------------------------------------------
__global__ void __launch_bounds__(256) front_k(
    const int* __restrict__ nbr_dst, int n_edges, int ngroups, int chk,
    unsigned* __restrict__ cnt,
    const float* __restrict__ x, const float* __restrict__ w,
    const float* __restrict__ b, __half* __restrict__ h16, int n_nodes)
{
    __shared__ __align__(16) char smem[GMAX * 4];   // 16KB union
    const int blk = blockIdx.x;
    const int tid = threadIdx.x;
    const int lane = tid & 63;
    const int wid = tid >> 6;

    if (blk < NSC) {
        unsigned* cnt_s = (unsigned*)smem;
        const int c = blk;
        const int e0 = c * chk;
        const int e1 = min(e0 + chk, n_edges);
        const int m = max(e1 - e0, 0);
        for (int g = tid; g < ngroups; g += 256) cnt_s[g] = 0u;
        __syncthreads();
        for (int i = tid; i < m; i += 256)
            atomicAdd(&cnt_s[(unsigned)nbr_dst[e0 + i] >> GSH], 1u);
        __syncthreads();
        const size_t ob = (size_t)c * ngroups;
        for (int g = tid; g < ngroups; g += 256) cnt[ob + g] = cnt_s[g];
    } else {
        _Float16 (*stile)[16][72] = (_Float16(*)[16][72])smem;
        const int col = lane & 15;
        const int quad = lane >> 4;
        f16x8 bw[4][2];
        float bv[4];
        #pragma unroll
        for (int t = 0; t < 4; ++t) {
            #pragma unroll
            for (int kb = 0; kb < 2; ++kb)
                bw[t][kb] = load_wfrag(w, 16 * t + col, kb * 32 + quad * 8);
            bv[t] = b[16 * t + col];
        }
        const int pb = blk - NSC;
        const int pgrid = gridDim.x - NSC;
        const int ntiles = (n_nodes + 15) >> 4;
        for (int tile = pb * 4 + wid; tile < ntiles; tile += pgrid * 4) {
            const int n0 = tile << 4;
            const int nr = min(n0 + col, n_nodes - 1);
            f16x8 a[2];
            #pragma unroll
            for (int kb = 0; kb < 2; ++kb)
                a[kb] = load_afrag_f32(x + (size_t)nr * NF + kb * 32 + quad * 8);
            f32x4 acc[4];
            #pragma unroll
            for (int t = 0; t < 4; ++t) acc[t] = (f32x4){bv[t], bv[t], bv[t], bv[t]};
            #pragma unroll
            for (int t = 0; t < 4; ++t)
                #pragma unroll
                for (int kb = 0; kb < 2; ++kb)
                    acc[t] = __builtin_amdgcn_mfma_f32_16x16x32_f16(a[kb], bw[t][kb], acc[t], 0, 0, 0);
            #pragma unroll
            for (int t = 0; t < 4; ++t)
                #pragma unroll
                for (int r = 0; r < 4; ++r)
                    stile[wid][quad * 4 + r][16 * t + col] = (_Float16)acc[t][r];
            __threadfence_block();
            #pragma unroll
            for (int it = 0; it < 2; ++it) {
                const int chunk = it * 64 + lane;
                const int row = chunk >> 3;
                const int off = (chunk & 7) * 8;
                const int n = n0 + row;
                if (n < n_nodes)
                    *(uint4*)(h16 + (size_t)n * NF + off) = *(const uint4*)&stile[wid][row][off];
            }
            __threadfence_block();
        }
    }
}

// ---------------------------------------------------------------------------
// colscan: per group g, exclusive scan of cnt[c][g] along c (NSC=256, 4/lane)
// ---------------------------------------------------------------------------
__global__ void __launch_bounds__(64) colscan_k(const unsigned* __restrict__ cnt,
                                                unsigned* __restrict__ colpre,
                                                unsigned* __restrict__ tot, int ngroups) {
    const int g = blockIdx.x;
    const int lane = threadIdx.x;
    unsigned v[4];
    unsigned s = 0u;
    #pragma unroll
    for (int j = 0; j < 4; ++j) {
        v[j] = cnt[(size_t)(4 * lane + j) * ngroups + g];
        s += v[j];
    }
    unsigned run = s;
    #pragma unroll
    for (int d = 1; d < 64; d <<= 1) {
        const unsigned t = __shfl_up(run, d, 64);
        if (lane >= d) run += t;
    }
    unsigned pre = run - s;
    #pragma unroll
    for (int j = 0; j < 4; ++j) {
        colpre[(size_t)(4 * lane + j) * ngroups + g] = pre;
        pre += v[j];
    }
    if (lane == 63) tot[g] = run;
}

// ---------------------------------------------------------------------------
// base: exclusive scan over group totals -> gbase[0..ngroups]
// ---------------------------------------------------------------------------
__global__ void __launch_bounds__(64) base_k(const unsigned* __restrict__ tot,
                                             unsigned* __restrict__ gbase, int ngroups) {
    const int lane = threadIdx.x;
    unsigned carry = 0u;
    for (int base = 0; base < ngroups; base += 64) {
        const int g = base + lane;
        const unsigned v = (g < ngroups) ? tot[g] : 0u;
        unsigned run = v;
        #pragma unroll
        for (int d = 1; d < 64; d <<= 1) {
            const unsigned t = __shfl_up(run, d, 64);
            if (lane >= d) run += t;
        }
        if (g < ngroups) gbase[g] = carry + run - v;
        carry += (unsigned)__shfl((int)run, 63, 64);
    }
    if (lane == 0) gbase[ngroups] = carry;
}

// ---------------------------------------------------------------------------
// scatter2: write records to FINAL globally-sorted-by-group positions.
// rec: lo = i0<<7 (tab row byte offset) ; hi = (src<<7)|dstrow(5b)
// ---------------------------------------------------------------------------
__global__ void __launch_bounds__(1024) scatter2_k(const int* __restrict__ nbr,
                                                   const float* __restrict__ dist,
                                                   int n_edges, int ngroups, int chk,
                                                   const unsigned* __restrict__ colpre,
                                                   const unsigned* __restrict__ gbase,
                                                   ull* __restrict__ payload) {
    __shared__ unsigned cur_s[GMAX];
    const int tid = threadIdx.x;
    const int c = blockIdx.x;
    const int e0 = c * chk;
    const int e1 = min(e0 + chk, n_edges);
    const int m = max(e1 - e0, 0);
    const size_t ob = (size_t)c * ngroups;
    for (int g = tid; g < ngroups; g += 1024) cur_s[g] = gbase[g] + colpre[ob + g];
    __syncthreads();
    const float scale = (float)(TBL - 1) / CUTF;
    for (int i = tid; i < m; i += 1024) {
        const int e = e0 + i;
        const unsigned dst = (unsigned)nbr[n_edges + e];
        const unsigned src = (unsigned)nbr[e];
        const float xx = dist[e] * scale + 0.5f;
        int i0 = (int)xx;
        i0 = max(0, min(i0, TBL - 1));
        const ull rec = (ull)((unsigned)i0 << 7) |
                        ((ull)((src << 7) | (dst & (GRP - 1u))) << 32);
        const unsigned pos = atomicAdd(&cur_s[dst >> GSH], 1u);
        payload[pos] = rec;
    }
}

// ---------------------------------------------------------------------------
// agg: block = 32-node group. Register-staged single read + count, row-sort
// into LDS, then pure gather-accumulate with 16-deep load pipelining.
// ---------------------------------------------------------------------------
__global__ void __launch_bounds__(256) agg_k(
    const ull* __restrict__ payload, const unsigned* __restrict__ gbase,
    const __half* __restrict__ h16, const __half* __restrict__ tabnn,
    float* __restrict__ agg, int n_nodes)
{
    __shared__ ull sorted_s[SCAP];
    __shared__ unsigned cnt_s[GRP];
    __shared__ unsigned base_s[GRP];
    __shared__ unsigned cur_s[GRP];
    const int tid = threadIdx.x;
    const int lane = tid & 63;
    const int wid = tid >> 6;   // 0..3
    const int g = blockIdx.x;
    const unsigned beg = gbase[g];
    const unsigned end = gbase[g + 1];
    const unsigned tot = min(end - beg, (unsigned)SCAP);

    if (tid < GRP) cnt_s[tid] = 0u;
    __syncthreads();
    // Phase A: stage records in registers (coalesced), count rows
    ull rec[RPT];
    #pragma unroll
    for (int k = 0; k < RPT; ++k) {
        const unsigned i = (unsigned)(k * 256) + tid;
        rec[k] = 0ull;
        if (i < tot) {
            rec[k] = payload[beg + i];
            atomicAdd(&cnt_s[(unsigned)(rec[k] >> 32) & (GRP - 1u)], 1u);
        }
    }
    __syncthreads();
    // exclusive scan over GRP row counts (lanes 0..GRP-1 of wave 0)
    if (tid < GRP) {
        const unsigned c = cnt_s[tid];
        unsigned run = c;
        #pragma unroll
        for (int d = 1; d < GRP; d <<= 1) {
            const unsigned t = __shfl_up(run, d, 64);
            if (tid >= d) run += t;
        }
        base_s[tid] = run - c;
        cur_s[tid]  = run - c;
    }
    __syncthreads();
    // Phase B: place by row (registers -> LDS)
    #pragma unroll
    for (int k = 0; k < RPT; ++k) {
        const unsigned i = (unsigned)(k * 256) + tid;
        if (i < tot) {
            const unsigned pos = atomicAdd(&cur_s[(unsigned)(rec[k] >> 32) & (GRP - 1u)], 1u);
            sorted_s[pos] = rec[k];
        }
    }
    __syncthreads();
    // Phase C: gather-accumulate; one coalesced store per row
    const char* tabB = (const char*)tabnn + (lane << 1);
    const char* hB   = (const char*)h16 + (lane << 1);
    auto ev = [&](ull r) -> float {
        const unsigned lo = (unsigned)r;          // tab row byte offset
        const unsigned hi = (unsigned)(r >> 32);
        const float tv = __half2float(*(const __half*)(tabB + lo));
        const float hv = __half2float(*(const __half*)(hB + (hi & 0xFFFFFF80u)));
        return tv * hv;
    };
    const int n0 = g * GRP;
    for (int rr = 0; rr < GRP / 4; ++rr) {
        const int r = wid * (GRP / 4) + rr;
        unsigned i = base_s[r];
        const unsigned e = cur_s[r];
        float acc0 = 0.f, acc1 = 0.f;
        for (; i + 16u <= e; i += 16u) {
            ull rv[16];
            #pragma unroll
            for (int j = 0; j < 16; ++j) rv[j] = sorted_s[i + j];
            float p[16];
            #pragma unroll
            for (int j = 0; j < 16; ++j) p[j] = ev(rv[j]);
            acc0 += ((p[0] + p[1]) + (p[2] + p[3])) + ((p[4] + p[5]) + (p[6] + p[7]));
            acc1 += ((p[8] + p[9]) + (p[10] + p[11])) + ((p[12] + p[13]) + (p[14] + p[15]));
        }
        for (; i + 4u <= e; i += 4u) {
            const ull r0 = sorted_s[i];
            const ull r1 = sorted_s[i + 1];
            const ull r2 = sorted_s[i + 2];
            const ull r3 = sorted_s[i + 3];
            acc0 += ev(r0) + ev(r1);
            acc1 += ev(r2) + ev(r3);
        }
        for (; i < e; ++i) acc0 += ev(sorted_s[i]);
        const int n = n0 + r;
        if (n < n_nodes) agg[(size_t)n * NF + lane] = acc0 + acc1;
    }
}

// ---------------------------------------------------------------------------
// overflow fixup: groups with >SCAP records (normally zero work)
// ---------------------------------------------------------------------------
__global__ void __launch_bounds__(64) oflow2_k(const ull* __restrict__ payload,
                                               const unsigned* __restrict__ gbase,
                                               const __half* __restrict__ h16,
                                               const __half* __restrict__ tabnn,
                                               float* __restrict__ agg) {
    const int g = blockIdx.x;
    const unsigned beg = gbase[g];
    const unsigned end = gbase[g + 1];
    if (end - beg <= (unsigned)SCAP) return;
    const int lane = threadIdx.x;
    const char* tabB = (const char*)tabnn + (lane << 1);
    const char* hB   = (const char*)h16 + (lane << 1);
    for (unsigned i = beg + SCAP; i < end; ++i) {
        const ull rec = payload[i];
        const unsigned lo = (unsigned)rec;
        const unsigned hi = (unsigned)(rec >> 32);
        const float tv = __half2float(*(const __half*)(tabB + lo));
        const float hv = __half2float(*(const __half*)(hB + (hi & 0xFFFFFF80u)));
        const unsigned row = (unsigned)g * GRP + (hi & (GRP - 1u));
        atomicAdd(agg + (size_t)row * NF + lane, tv * hv);
    }
}

// ---------------------------------------------------------------------------
// fallback edge kernel (direct atomic scatter-add) — used only if ws too small
// ---------------------------------------------------------------------------
__global__ void edge_k(const int* __restrict__ nbr, const float* __restrict__ dist,
                       const __half* __restrict__ h16, const __half* __restrict__ tabnn,
                       float* __restrict__ agg, int n_edges) {
    const int tid = threadIdx.x;
    const int lane = tid & 63;
    const int nwaves = (gridDim.x * blockDim.x) >> 6;
    const int gw = (blockIdx.x * blockDim.x + tid) >> 6;
    const float scale = (float)(TBL - 1) / CUTF;
    const int nbatch = n_edges >> 6;
    for (int bb = gw; bb < nbatch; bb += nwaves) {
        const int e0 = bb << 6;
        int src = nbr[e0 + lane];
        int dst = nbr[n_edges + e0 + lane];
        float d = dist[e0 + lane];
        float xx = d * scale + 0.5f;
        int i0 = (int)xx;
        i0 = max(0, min(i0, TBL - 1));
        #pragma unroll 4
        for (int j = 0; j < 64; ++j) {
            const int sj = __shfl(src, j);
            const int dj = __shfl(dst, j);
            const int ij = __shfl(i0, j);
            const float tv = __half2float(tabnn[(size_t)ij * NF + lane]);
            const float hv = __half2float(h16[(size_t)sj * NF + lane]);
            atomicAdd(agg + (size_t)dj * NF + lane, tv * hv);
        }
    }
    if (gw == 0) {
        for (int e = nbatch << 6; e < n_edges; ++e) {
            const int sj = nbr[e];
            const int dj = nbr[n_edges + e];
            const float d = dist[e];
            float xx = d * scale + 0.5f;
            int ij = (int)xx;
            ij = max(0, min(ij, TBL - 1));
            const float tv = __half2float(tabnn[(size_t)ij * NF + lane]);
            const float hv = __half2float(h16[(size_t)sj * NF + lane]);
            atomicAdd(agg + (size_t)dj * NF + lane, tv * hv);
        }
    }
}

// ---------------------------------------------------------------------------
// out_mlp (MFMA): out = ssp(agg@W1^T+b1)@W2^T+b2. Wave per 16-node tile.
// ---------------------------------------------------------------------------
__global__ void __launch_bounds__(256) out_mlp_k(const float* __restrict__ agg,
                                                 const float* __restrict__ w1,
                                                 const float* __restrict__ b1,
                                                 const float* __restrict__ w2,
                                                 const float* __restrict__ b2,
                                                 float* __restrict__ out, int n_nodes) {
    __shared__ _Float16 stile[4][16][72];
    const int tid = threadIdx.x;
    const int lane = tid & 63;
    const int wid = tid >> 6;
    const int col = lane & 15;
    const int quad = lane >> 4;

    f16x8 bw1[4][2], bw2[4][2];
    float b1v[4], b2v[4];
    #pragma unroll
    for (int t = 0; t < 4; ++t) {
        #pragma unroll
        for (int kb = 0; kb < 2; ++kb) {
            bw1[t][kb] = load_wfrag(w1, 16 * t + col, kb * 32 + quad * 8);
            bw2[t][kb] = load_wfrag(w2, 16 * t + col, kb * 32 + quad * 8);
        }
        b1v[t] = b1[16 * t + col];
        b2v[t] = b2[16 * t + col];
    }

    const int ntiles = (n_nodes + 15) >> 4;
    for (int tile = blockIdx.x * 4 + wid; tile < ntiles; tile += gridDim.x * 4) {
        const int n0 = tile << 4;
        const int nr = min(n0 + col, n_nodes - 1);
        f16x8 a[2];
        #pragma unroll
        for (int kb = 0; kb < 2; ++kb)
            a[kb] = load_afrag_f32(agg + (size_t)nr * NF + kb * 32 + quad * 8);
        f32x4 acc[4];
        #pragma unroll
        for (int t = 0; t < 4; ++t) acc[t] = (f32x4){b1v[t], b1v[t], b1v[t], b1v[t]};
        #pragma unroll
        for (int t = 0; t < 4; ++t)
            #pragma unroll
            for (int kb = 0; kb < 2; ++kb)
                acc[t] = __builtin_amdgcn_mfma_f32_16x16x32_f16(a[kb], bw1[t][kb], acc[t], 0, 0, 0);
        #pragma unroll
        for (int t = 0; t < 4; ++t)
            #pragma unroll
            for (int r = 0; r < 4; ++r)
                stile[wid][quad * 4 + r][16 * t + col] = (_Float16)sspf(acc[t][r]);
        __threadfence_block();
        f16x8 a2[2];
        #pragma unroll
        for (int kb = 0; kb < 2; ++kb)
            a2[kb] = *(const f16x8*)&stile[wid][col][kb * 32 + quad * 8];
        f32x4 acc2[4];
        #pragma unroll
        for (int t = 0; t < 4; ++t) acc2[t] = (f32x4){b2v[t], b2v[t], b2v[t], b2v[t]};
        #pragma unroll
        for (int t = 0; t < 4; ++t)
            #pragma unroll
            for (int kb = 0; kb < 2; ++kb)
                acc2[t] = __builtin_amdgcn_mfma_f32_16x16x32_f16(a2[kb], bw2[t][kb], acc2[t], 0, 0, 0);
        #pragma unroll
        for (int t = 0; t < 4; ++t)
            #pragma unroll
            for (int r = 0; r < 4; ++r) {
                const int n = n0 + quad * 4 + r;
                if (n < n_nodes) out[(size_t)n * NF + 16 * t + col] = acc2[t][r];
            }
        __threadfence_block();
    }
}

extern "C" void kernel_launch(void* const* d_in, const int* in_sizes, int n_in,
                              void* d_out, int out_size, void* d_ws, size_t ws_size,
                              hipStream_t stream) {
    const int*   nbr   = (const int*)d_in[0];
    const float* dist  = (const float*)d_in[1];
    const float* x     = (const float*)d_in[2];
    const float* lin_w = (const float*)d_in[3];
    const float* lin_b = (const float*)d_in[4];
    const float* f_w1  = (const float*)d_in[5];
    const float* f_b1  = (const float*)d_in[6];
    const float* f_w2  = (const float*)d_in[7];
    const float* f_b2  = (const float*)d_in[8];
    const float* m_w1  = (const float*)d_in[9];
    const float* m_b1  = (const float*)d_in[10];
    const float* m_w2  = (const float*)d_in[11];
    const float* m_b2  = (const float*)d_in[12];

    const int n_edges = in_sizes[1];
    const int n_nodes = in_sizes[2] / NF;
    const int ngroups = (n_nodes + GRP - 1) / GRP;
    const int chk     = (n_edges + NSC - 1) / NSC;
    const int ntiles  = (n_nodes + 15) / 16;
    const int mlp_blk = (ntiles + 3) / 4;

    float* out = (float*)d_out;
    float* agg = out;   // agg lives in d_out; out_mlp runs in place

    // workspace: h16 | tabnn | cnt | colpre | tot | gbase | payload
    char* ws = (char*)d_ws;
    size_t off = 0;
    auto alloc = [&](size_t bytes) { char* p = ws + off; off = (off + bytes + 255) & ~(size_t)255; return p; };
    __half*   h16     = (__half*)alloc((size_t)n_nodes * NF * sizeof(__half));
    __half*   tabnn   = (__half*)alloc((size_t)TBL * NF * sizeof(__half));
    unsigned* cnt     = (unsigned*)alloc((size_t)NSC * ngroups * sizeof(unsigned));
    unsigned* colpre  = (unsigned*)alloc((size_t)NSC * ngroups * sizeof(unsigned));
    unsigned* tot     = (unsigned*)alloc((size_t)ngroups * sizeof(unsigned));
    unsigned* gbase   = (unsigned*)alloc((size_t)(ngroups + 1) * sizeof(unsigned));
    ull*      payload = (ull*)alloc((size_t)NSC * chk * sizeof(ull));
    const bool sort_path = (off <= ws_size) && (ngroups <= GMAX) && (n_nodes <= (1 << 17));

    build_tabnn_k<<<TBL / 64, 256, 0, stream>>>(f_w1, f_b1, f_w2, f_b2, tabnn);
    // fused front end: hist + prep (both register-light)
    front_k<<<NSC + mlp_blk, 256, 0, stream>>>(
        nbr + n_edges, n_edges, ngroups, chk, cnt,
        x, lin_w, lin_b, h16, n_nodes);

    if (sort_path) {
        colscan_k<<<ngroups, 64, 0, stream>>>(cnt, colpre, tot, ngroups);
        base_k<<<1, 64, 0, stream>>>(tot, gbase, ngroups);
        scatter2_k<<<NSC, 1024, 0, stream>>>(nbr, dist, n_edges, ngroups, chk,
                                             colpre, gbase, payload);
        agg_k<<<ngroups, 256, 0, stream>>>(payload, gbase, h16, tabnn, agg, n_nodes);
        oflow2_k<<<ngroups, 64, 0, stream>>>(payload, gbase, h16, tabnn, agg);
    } else {
        hipMemsetAsync(agg, 0, (size_t)n_nodes * NF * sizeof(float), stream);
        edge_k<<<2048, 256, 0, stream>>>(nbr, dist, h16, tabnn, agg, n_edges);
    }
    out_mlp_k<<<mlp_blk, 256, 0, stream>>>(agg, m_w1, m_b1, m_w2, m_b2, out, n_nodes);
}

// Round 25
// 173.255 us; speedup vs baseline: 1.2453x; 1.1149x over previous
//
#include <hip/hip_runtime.h>
#include <hip/hip_fp16.h>

#define NF 64
#define KEXP 50
#define TBL 16384           // nearest-neighbor fp16 table (2MB)
#define CUTF 5.0f
#define LOG2C 0.6931471805599453f
#define GRP 32              // nodes per group (agg block granule)
#define GSH 5               // log2(GRP)
#define NSC 256             // superchunks (sort blocks)
#define GMAX 4096           // max node-groups (LDS histogram bound)
#define SCAP 768            // max records per group (mean 512, +11 sigma)
#define RPT (SCAP / 256)    // records per thread staged in registers
#define MLPB 512            // blocks for tile-loop MLP kernels (amortize weights)

typedef unsigned long long ull;
typedef _Float16 f16x8 __attribute__((ext_vector_type(8)));
typedef float f32x4 __attribute__((ext_vector_type(4)));

__device__ __forceinline__ float sspf(float x) {
    // fast softplus(x) - log2
    return fmaxf(x, 0.0f) + __logf(1.0f + __expf(-fabsf(x))) - LOG2C;
}

// load 8 consecutive fp32 from row-major w[f][k0..k0+7] as f16x8 (MFMA B-frag)
__device__ __forceinline__ f16x8 load_wfrag(const float* __restrict__ w, int f, int k0) {
    const float4 q0 = *(const float4*)(w + (size_t)f * NF + k0);
    const float4 q1 = *(const float4*)(w + (size_t)f * NF + k0 + 4);
    f16x8 r;
    r[0] = (_Float16)q0.x; r[1] = (_Float16)q0.y; r[2] = (_Float16)q0.z; r[3] = (_Float16)q0.w;
    r[4] = (_Float16)q1.x; r[5] = (_Float16)q1.y; r[6] = (_Float16)q1.z; r[7] = (_Float16)q1.w;
    return r;
}

__device__ __forceinline__ f16x8 load_afrag_f32(const float* __restrict__ p) {
    const float4 q0 = *(const float4*)(p);
    const float4 q1 = *(const float4*)(p + 4);
    f16x8 r;
    r[0] = (_Float16)q0.x; r[1] = (_Float16)q0.y; r[2] = (_Float16)q0.z; r[3] = (_Float16)q0.w;
    r[4] = (_Float16)q1.x; r[5] = (_Float16)q1.y; r[6] = (_Float16)q1.z; r[7] = (_Float16)q1.w;
    return r;
}

// ---------------------------------------------------------------------------
// table build (standalone; register-fat by design): 256 blocks x 256 thr.
// ---------------------------------------------------------------------------
__global__ void __launch_bounds__(256) build_tabnn_k(
    const float* __restrict__ f_w1, const float* __restrict__ f_b1,
    const float* __restrict__ f_w2, const float* __restrict__ f_b2,
    __half* __restrict__ tabnn) {
    const int tid = threadIdx.x;
    const int lane = tid & 63;
    const int wid = tid >> 6;
    float w1r[KEXP], w2r[NF];
    for (int k = 0; k < KEXP; ++k) w1r[k] = f_w1[lane * KEXP + k];
    for (int k = 0; k < NF; ++k)  w2r[k] = f_w2[lane * NF + k];
    const float b1 = f_b1[lane], b2 = f_b2[lane];
    const float delta = CUTF / (float)(KEXP - 1);
    const float coeff = -0.5f / (delta * delta);
    const float dstep = CUTF / (float)(TBL - 1);
    for (int tt = 0; tt < 16; ++tt) {
        const int t = blockIdx.x * 64 + wid * 16 + tt;
        const float d = (float)t * dstep;
        float rbfv = 0.f;
        if (lane < KEXP) {
            const float dd = d - (float)lane * delta;
            rbfv = __expf(coeff * dd * dd);
        }
        float t1 = b1;
        for (int k = 0; k < KEXP; ++k) t1 = fmaf(__shfl(rbfv, k), w1r[k], t1);
        const float sv = sspf(t1);
        float t2 = b2;
        for (int k = 0; k < NF; ++k) t2 = fmaf(__shfl(sv, k), w2r[k], t2);
        tabnn[(size_t)t * NF + lane] = __float2half(t2);
    }
}

// ---------------------------------------------------------------------------
// front_k: fused [hist | prep] — both register-light. Prep portion uses a
// small grid so each wave loops ~3 tiles, amortizing the weight preload.
// ---------------------------------------------------------------------------
__global__ void __launch_bounds__(256) front_k(
    const int* __restrict__ nbr_dst, int n_edges, int ngroups, int chk,
    unsigned* __restrict__ cnt,
    const float* __restrict__ x, const float* __restrict__ w,
    const float* __restrict__ b, __half* __restrict__ h16, int n_nodes)
{
    __shared__ __align__(16) char smem[GMAX * 4];   // 16KB union
    const int blk = blockIdx.x;
    const int tid = threadIdx.x;
    const int lane = tid & 63;
    const int wid = tid >> 6;

    if (blk < NSC) {
        unsigned* cnt_s = (unsigned*)smem;
        const int c = blk;
        const int e0 = c * chk;
        const int e1 = min(e0 + chk, n_edges);
        const int m = max(e1 - e0, 0);
        for (int g = tid; g < ngroups; g += 256) cnt_s[g] = 0u;
        __syncthreads();
        for (int i = tid; i < m; i += 256)
            atomicAdd(&cnt_s[(unsigned)nbr_dst[e0 + i] >> GSH], 1u);
        __syncthreads();
        const size_t ob = (size_t)c * ngroups;
        for (int g = tid; g < ngroups; g += 256) cnt[ob + g] = cnt_s[g];
    } else {
        _Float16 (*stile)[16][72] = (_Float16(*)[16][72])smem;
        const int col = lane & 15;
        const int quad = lane >> 4;
        f16x8 bw[4][2];
        float bv[4];
        #pragma unroll
        for (int t = 0; t < 4; ++t) {
            #pragma unroll
            for (int kb = 0; kb < 2; ++kb)
                bw[t][kb] = load_wfrag(w, 16 * t + col, kb * 32 + quad * 8);
            bv[t] = b[16 * t + col];
        }
        const int pb = blk - NSC;
        const int pgrid = gridDim.x - NSC;
        const int ntiles = (n_nodes + 15) >> 4;
        for (int tile = pb * 4 + wid; tile < ntiles; tile += pgrid * 4) {
            const int n0 = tile << 4;
            const int nr = min(n0 + col, n_nodes - 1);
            f16x8 a[2];
            #pragma unroll
            for (int kb = 0; kb < 2; ++kb)
                a[kb] = load_afrag_f32(x + (size_t)nr * NF + kb * 32 + quad * 8);
            f32x4 acc[4];
            #pragma unroll
            for (int t = 0; t < 4; ++t) acc[t] = (f32x4){bv[t], bv[t], bv[t], bv[t]};
            #pragma unroll
            for (int t = 0; t < 4; ++t)
                #pragma unroll
                for (int kb = 0; kb < 2; ++kb)
                    acc[t] = __builtin_amdgcn_mfma_f32_16x16x32_f16(a[kb], bw[t][kb], acc[t], 0, 0, 0);
            #pragma unroll
            for (int t = 0; t < 4; ++t)
                #pragma unroll
                for (int r = 0; r < 4; ++r)
                    stile[wid][quad * 4 + r][16 * t + col] = (_Float16)acc[t][r];
            __threadfence_block();
            #pragma unroll
            for (int it = 0; it < 2; ++it) {
                const int chunk = it * 64 + lane;
                const int row = chunk >> 3;
                const int off = (chunk & 7) * 8;
                const int n = n0 + row;
                if (n < n_nodes)
                    *(uint4*)(h16 + (size_t)n * NF + off) = *(const uint4*)&stile[wid][row][off];
            }
            __threadfence_block();
        }
    }
}

// ---------------------------------------------------------------------------
// colscan: per group g, exclusive scan of cnt[c][g] along c (NSC=256, 4/lane)
// ---------------------------------------------------------------------------
__global__ void __launch_bounds__(64) colscan_k(const unsigned* __restrict__ cnt,
                                                unsigned* __restrict__ colpre,
                                                unsigned* __restrict__ tot, int ngroups) {
    const int g = blockIdx.x;
    const int lane = threadIdx.x;
    unsigned v[4];
    unsigned s = 0u;
    #pragma unroll
    for (int j = 0; j < 4; ++j) {
        v[j] = cnt[(size_t)(4 * lane + j) * ngroups + g];
        s += v[j];
    }
    unsigned run = s;
    #pragma unroll
    for (int d = 1; d < 64; d <<= 1) {
        const unsigned t = __shfl_up(run, d, 64);
        if (lane >= d) run += t;
    }
    unsigned pre = run - s;
    #pragma unroll
    for (int j = 0; j < 4; ++j) {
        colpre[(size_t)(4 * lane + j) * ngroups + g] = pre;
        pre += v[j];
    }
    if (lane == 63) tot[g] = run;
}

// ---------------------------------------------------------------------------
// base: exclusive scan over group totals -> gbase[0..ngroups]
// ---------------------------------------------------------------------------
__global__ void __launch_bounds__(64) base_k(const unsigned* __restrict__ tot,
                                             unsigned* __restrict__ gbase, int ngroups) {
    const int lane = threadIdx.x;
    unsigned carry = 0u;
    for (int base = 0; base < ngroups; base += 64) {
        const int g = base + lane;
        const unsigned v = (g < ngroups) ? tot[g] : 0u;
        unsigned run = v;
        #pragma unroll
        for (int d = 1; d < 64; d <<= 1) {
            const unsigned t = __shfl_up(run, d, 64);
            if (lane >= d) run += t;
        }
        if (g < ngroups) gbase[g] = carry + run - v;
        carry += (unsigned)__shfl((int)run, 63, 64);
    }
    if (lane == 0) gbase[ngroups] = carry;
}

// ---------------------------------------------------------------------------
// scatter2: write records to FINAL globally-sorted-by-group positions.
// rec: lo = i0<<7 (tab row byte offset) ; hi = (src<<7)|dstrow(5b)
// ---------------------------------------------------------------------------
__global__ void __launch_bounds__(1024) scatter2_k(const int* __restrict__ nbr,
                                                   const float* __restrict__ dist,
                                                   int n_edges, int ngroups, int chk,
                                                   const unsigned* __restrict__ colpre,
                                                   const unsigned* __restrict__ gbase,
                                                   ull* __restrict__ payload) {
    __shared__ unsigned cur_s[GMAX];
    const int tid = threadIdx.x;
    const int c = blockIdx.x;
    const int e0 = c * chk;
    const int e1 = min(e0 + chk, n_edges);
    const int m = max(e1 - e0, 0);
    const size_t ob = (size_t)c * ngroups;
    for (int g = tid; g < ngroups; g += 1024) cur_s[g] = gbase[g] + colpre[ob + g];
    __syncthreads();
    const float scale = (float)(TBL - 1) / CUTF;
    for (int i = tid; i < m; i += 1024) {
        const int e = e0 + i;
        const unsigned dst = (unsigned)nbr[n_edges + e];
        const unsigned src = (unsigned)nbr[e];
        const float xx = dist[e] * scale + 0.5f;
        int i0 = (int)xx;
        i0 = max(0, min(i0, TBL - 1));
        const ull rec = (ull)((unsigned)i0 << 7) |
                        ((ull)((src << 7) | (dst & (GRP - 1u))) << 32);
        const unsigned pos = atomicAdd(&cur_s[dst >> GSH], 1u);
        payload[pos] = rec;
    }
}

// ---------------------------------------------------------------------------
// agg: block = 32-node group. Register-staged single read + count, row-sort
// into LDS, then pure gather-accumulate with 16-deep load pipelining.
// ---------------------------------------------------------------------------
__global__ void __launch_bounds__(256) agg_k(
    const ull* __restrict__ payload, const unsigned* __restrict__ gbase,
    const __half* __restrict__ h16, const __half* __restrict__ tabnn,
    float* __restrict__ agg, int n_nodes)
{
    __shared__ ull sorted_s[SCAP];
    __shared__ unsigned cnt_s[GRP];
    __shared__ unsigned base_s[GRP];
    __shared__ unsigned cur_s[GRP];
    const int tid = threadIdx.x;
    const int lane = tid & 63;
    const int wid = tid >> 6;   // 0..3
    const int g = blockIdx.x;
    const unsigned beg = gbase[g];
    const unsigned end = gbase[g + 1];
    const unsigned tot = min(end - beg, (unsigned)SCAP);

    if (tid < GRP) cnt_s[tid] = 0u;
    __syncthreads();
    // Phase A: stage records in registers (coalesced), count rows
    ull rec[RPT];
    #pragma unroll
    for (int k = 0; k < RPT; ++k) {
        const unsigned i = (unsigned)(k * 256) + tid;
        rec[k] = 0ull;
        if (i < tot) {
            rec[k] = payload[beg + i];
            atomicAdd(&cnt_s[(unsigned)(rec[k] >> 32) & (GRP - 1u)], 1u);
        }
    }
    __syncthreads();
    // exclusive scan over GRP row counts (lanes 0..GRP-1 of wave 0)
    if (tid < GRP) {
        const unsigned c = cnt_s[tid];
        unsigned run = c;
        #pragma unroll
        for (int d = 1; d < GRP; d <<= 1) {
            const unsigned t = __shfl_up(run, d, 64);
            if (tid >= d) run += t;
        }
        base_s[tid] = run - c;
        cur_s[tid]  = run - c;
    }
    __syncthreads();
    // Phase B: place by row (registers -> LDS)
    #pragma unroll
    for (int k = 0; k < RPT; ++k) {
        const unsigned i = (unsigned)(k * 256) + tid;
        if (i < tot) {
            const unsigned pos = atomicAdd(&cur_s[(unsigned)(rec[k] >> 32) & (GRP - 1u)], 1u);
            sorted_s[pos] = rec[k];
        }
    }
    __syncthreads();
    // Phase C: gather-accumulate; one coalesced store per row
    const char* tabB = (const char*)tabnn + (lane << 1);
    const char* hB   = (const char*)h16 + (lane << 1);
    auto ev = [&](ull r) -> float {
        const unsigned lo = (unsigned)r;          // tab row byte offset
        const unsigned hi = (unsigned)(r >> 32);
        const float tv = __half2float(*(const __half*)(tabB + lo));
        const float hv = __half2float(*(const __half*)(hB + (hi & 0xFFFFFF80u)));
        return tv * hv;
    };
    const int n0 = g * GRP;
    for (int rr = 0; rr < GRP / 4; ++rr) {
        const int r = wid * (GRP / 4) + rr;
        unsigned i = base_s[r];
        const unsigned e = cur_s[r];
        float acc0 = 0.f, acc1 = 0.f;
        for (; i + 16u <= e; i += 16u) {
            ull rv[16];
            #pragma unroll
            for (int j = 0; j < 16; ++j) rv[j] = sorted_s[i + j];
            float p[16];
            #pragma unroll
            for (int j = 0; j < 16; ++j) p[j] = ev(rv[j]);
            acc0 += ((p[0] + p[1]) + (p[2] + p[3])) + ((p[4] + p[5]) + (p[6] + p[7]));
            acc1 += ((p[8] + p[9]) + (p[10] + p[11])) + ((p[12] + p[13]) + (p[14] + p[15]));
        }
        for (; i + 4u <= e; i += 4u) {
            const ull r0 = sorted_s[i];
            const ull r1 = sorted_s[i + 1];
            const ull r2 = sorted_s[i + 2];
            const ull r3 = sorted_s[i + 3];
            acc0 += ev(r0) + ev(r1);
            acc1 += ev(r2) + ev(r3);
        }
        for (; i < e; ++i) acc0 += ev(sorted_s[i]);
        const int n = n0 + r;
        if (n < n_nodes) agg[(size_t)n * NF + lane] = acc0 + acc1;
    }
}

// ---------------------------------------------------------------------------
// overflow fixup: groups with >SCAP records (normally zero work)
// ---------------------------------------------------------------------------
__global__ void __launch_bounds__(64) oflow2_k(const ull* __restrict__ payload,
                                               const unsigned* __restrict__ gbase,
                                               const __half* __restrict__ h16,
                                               const __half* __restrict__ tabnn,
                                               float* __restrict__ agg) {
    const int g = blockIdx.x;
    const unsigned beg = gbase[g];
    const unsigned end = gbase[g + 1];
    if (end - beg <= (unsigned)SCAP) return;
    const int lane = threadIdx.x;
    const char* tabB = (const char*)tabnn + (lane << 1);
    const char* hB   = (const char*)h16 + (lane << 1);
    for (unsigned i = beg + SCAP; i < end; ++i) {
        const ull rec = payload[i];
        const unsigned lo = (unsigned)rec;
        const unsigned hi = (unsigned)(rec >> 32);
        const float tv = __half2float(*(const __half*)(tabB + lo));
        const float hv = __half2float(*(const __half*)(hB + (hi & 0xFFFFFF80u)));
        const unsigned row = (unsigned)g * GRP + (hi & (GRP - 1u));
        atomicAdd(agg + (size_t)row * NF + lane, tv * hv);
    }
}

// ---------------------------------------------------------------------------
// fallback edge kernel (direct atomic scatter-add) — used only if ws too small
// ---------------------------------------------------------------------------
__global__ void edge_k(const int* __restrict__ nbr, const float* __restrict__ dist,
                       const __half* __restrict__ h16, const __half* __restrict__ tabnn,
                       float* __restrict__ agg, int n_edges) {
    const int tid = threadIdx.x;
    const int lane = tid & 63;
    const int nwaves = (gridDim.x * blockDim.x) >> 6;
    const int gw = (blockIdx.x * blockDim.x + tid) >> 6;
    const float scale = (float)(TBL - 1) / CUTF;
    const int nbatch = n_edges >> 6;
    for (int bb = gw; bb < nbatch; bb += nwaves) {
        const int e0 = bb << 6;
        int src = nbr[e0 + lane];
        int dst = nbr[n_edges + e0 + lane];
        float d = dist[e0 + lane];
        float xx = d * scale + 0.5f;
        int i0 = (int)xx;
        i0 = max(0, min(i0, TBL - 1));
        #pragma unroll 4
        for (int j = 0; j < 64; ++j) {
            const int sj = __shfl(src, j);
            const int dj = __shfl(dst, j);
            const int ij = __shfl(i0, j);
            const float tv = __half2float(tabnn[(size_t)ij * NF + lane]);
            const float hv = __half2float(h16[(size_t)sj * NF + lane]);
            atomicAdd(agg + (size_t)dj * NF + lane, tv * hv);
        }
    }
    if (gw == 0) {
        for (int e = nbatch << 6; e < n_edges; ++e) {
            const int sj = nbr[e];
            const int dj = nbr[n_edges + e];
            const float d = dist[e];
            float xx = d * scale + 0.5f;
            int ij = (int)xx;
            ij = max(0, min(ij, TBL - 1));
            const float tv = __half2float(tabnn[(size_t)ij * NF + lane]);
            const float hv = __half2float(h16[(size_t)sj * NF + lane]);
            atomicAdd(agg + (size_t)dj * NF + lane, tv * hv);
        }
    }
}

// ---------------------------------------------------------------------------
// out_mlp (MFMA): out = ssp(agg@W1^T+b1)@W2^T+b2. Wave per 16-node tile,
// ~3 tiles per wave (MLPB blocks) to amortize the weight preload.
// ---------------------------------------------------------------------------
__global__ void __launch_bounds__(256) out_mlp_k(const float* __restrict__ agg,
                                                 const float* __restrict__ w1,
                                                 const float* __restrict__ b1,
                                                 const float* __restrict__ w2,
                                                 const float* __restrict__ b2,
                                                 float* __restrict__ out, int n_nodes) {
    __shared__ _Float16 stile[4][16][72];
    const int tid = threadIdx.x;
    const int lane = tid & 63;
    const int wid = tid >> 6;
    const int col = lane & 15;
    const int quad = lane >> 4;

    f16x8 bw1[4][2], bw2[4][2];
    float b1v[4], b2v[4];
    #pragma unroll
    for (int t = 0; t < 4; ++t) {
        #pragma unroll
        for (int kb = 0; kb < 2; ++kb) {
            bw1[t][kb] = load_wfrag(w1, 16 * t + col, kb * 32 + quad * 8);
            bw2[t][kb] = load_wfrag(w2, 16 * t + col, kb * 32 + quad * 8);
        }
        b1v[t] = b1[16 * t + col];
        b2v[t] = b2[16 * t + col];
    }

    const int ntiles = (n_nodes + 15) >> 4;
    for (int tile = blockIdx.x * 4 + wid; tile < ntiles; tile += gridDim.x * 4) {
        const int n0 = tile << 4;
        const int nr = min(n0 + col, n_nodes - 1);
        f16x8 a[2];
        #pragma unroll
        for (int kb = 0; kb < 2; ++kb)
            a[kb] = load_afrag_f32(agg + (size_t)nr * NF + kb * 32 + quad * 8);
        f32x4 acc[4];
        #pragma unroll
        for (int t = 0; t < 4; ++t) acc[t] = (f32x4){b1v[t], b1v[t], b1v[t], b1v[t]};
        #pragma unroll
        for (int t = 0; t < 4; ++t)
            #pragma unroll
            for (int kb = 0; kb < 2; ++kb)
                acc[t] = __builtin_amdgcn_mfma_f32_16x16x32_f16(a[kb], bw1[t][kb], acc[t], 0, 0, 0);
        #pragma unroll
        for (int t = 0; t < 4; ++t)
            #pragma unroll
            for (int r = 0; r < 4; ++r)
                stile[wid][quad * 4 + r][16 * t + col] = (_Float16)sspf(acc[t][r]);
        __threadfence_block();
        f16x8 a2[2];
        #pragma unroll
        for (int kb = 0; kb < 2; ++kb)
            a2[kb] = *(const f16x8*)&stile[wid][col][kb * 32 + quad * 8];
        f32x4 acc2[4];
        #pragma unroll
        for (int t = 0; t < 4; ++t) acc2[t] = (f32x4){b2v[t], b2v[t], b2v[t], b2v[t]};
        #pragma unroll
        for (int t = 0; t < 4; ++t)
            #pragma unroll
            for (int kb = 0; kb < 2; ++kb)
                acc2[t] = __builtin_amdgcn_mfma_f32_16x16x32_f16(a2[kb], bw2[t][kb], acc2[t], 0, 0, 0);
        #pragma unroll
        for (int t = 0; t < 4; ++t)
            #pragma unroll
            for (int r = 0; r < 4; ++r) {
                const int n = n0 + quad * 4 + r;
                if (n < n_nodes) out[(size_t)n * NF + 16 * t + col] = acc2[t][r];
            }
        __threadfence_block();
    }
}

extern "C" void kernel_launch(void* const* d_in, const int* in_sizes, int n_in,
                              void* d_out, int out_size, void* d_ws, size_t ws_size,
                              hipStream_t stream) {
    const int*   nbr   = (const int*)d_in[0];
    const float* dist  = (const float*)d_in[1];
    const float* x     = (const float*)d_in[2];
    const float* lin_w = (const float*)d_in[3];
    const float* lin_b = (const float*)d_in[4];
    const float* f_w1  = (const float*)d_in[5];
    const float* f_b1  = (const float*)d_in[6];
    const float* f_w2  = (const float*)d_in[7];
    const float* f_b2  = (const float*)d_in[8];
    const float* m_w1  = (const float*)d_in[9];
    const float* m_b1  = (const float*)d_in[10];
    const float* m_w2  = (const float*)d_in[11];
    const float* m_b2  = (const float*)d_in[12];

    const int n_edges = in_sizes[1];
    const int n_nodes = in_sizes[2] / NF;
    const int ngroups = (n_nodes + GRP - 1) / GRP;
    const int chk     = (n_edges + NSC - 1) / NSC;
    const int ntiles  = (n_nodes + 15) / 16;
    const int mlp_blk = (ntiles + 3) / 4;
    const int tile_blk = mlp_blk < MLPB ? mlp_blk : MLPB;

    float* out = (float*)d_out;
    float* agg = out;   // agg lives in d_out; out_mlp runs in place

    // workspace: h16 | tabnn | cnt | colpre | tot | gbase | payload
    char* ws = (char*)d_ws;
    size_t off = 0;
    auto alloc = [&](size_t bytes) { char* p = ws + off; off = (off + bytes + 255) & ~(size_t)255; return p; };
    __half*   h16     = (__half*)alloc((size_t)n_nodes * NF * sizeof(__half));
    __half*   tabnn   = (__half*)alloc((size_t)TBL * NF * sizeof(__half));
    unsigned* cnt     = (unsigned*)alloc((size_t)NSC * ngroups * sizeof(unsigned));
    unsigned* colpre  = (unsigned*)alloc((size_t)NSC * ngroups * sizeof(unsigned));
    unsigned* tot     = (unsigned*)alloc((size_t)ngroups * sizeof(unsigned));
    unsigned* gbase   = (unsigned*)alloc((size_t)(ngroups + 1) * sizeof(unsigned));
    ull*      payload = (ull*)alloc((size_t)NSC * chk * sizeof(ull));
    const bool sort_path = (off <= ws_size) && (ngroups <= GMAX) && (n_nodes <= (1 << 17));

    build_tabnn_k<<<TBL / 64, 256, 0, stream>>>(f_w1, f_b1, f_w2, f_b2, tabnn);
    // fused front end: hist + prep (prep on a small grid, ~3 tiles/wave)
    front_k<<<NSC + tile_blk, 256, 0, stream>>>(
        nbr + n_edges, n_edges, ngroups, chk, cnt,
        x, lin_w, lin_b, h16, n_nodes);

    if (sort_path) {
        colscan_k<<<ngroups, 64, 0, stream>>>(cnt, colpre, tot, ngroups);
        base_k<<<1, 64, 0, stream>>>(tot, gbase, ngroups);
        scatter2_k<<<NSC, 1024, 0, stream>>>(nbr, dist, n_edges, ngroups, chk,
                                             colpre, gbase, payload);
        agg_k<<<ngroups, 256, 0, stream>>>(payload, gbase, h16, tabnn, agg, n_nodes);
        oflow2_k<<<ngroups, 64, 0, stream>>>(payload, gbase, h16, tabnn, agg);
    } else {
        hipMemsetAsync(agg, 0, (size_t)n_nodes * NF * sizeof(float), stream);
        edge_k<<<2048, 256, 0, stream>>>(nbr, dist, h16, tabnn, agg, n_edges);
    }
    out_mlp_k<<<tile_blk, 256, 0, stream>>>(agg, m_w1, m_b1, m_w2, m_b2, out, n_nodes);
}

// Round 26
// 170.299 us; speedup vs baseline: 1.2669x; 1.0174x over previous
//
#include <hip/hip_runtime.h>
#include <hip/hip_fp16.h>

#define NF 64
#define KEXP 50
#define TBL 16384           // nearest-neighbor fp16 table (2MB)
#define CUTF 5.0f
#define LOG2C 0.6931471805599453f
#define GRP 32              // nodes per group (agg block granule)
#define GSH 5               // log2(GRP)
#define NSC 256             // superchunks (sort blocks)
#define GMAX 4096           // max node-groups (LDS histogram bound)
#define SCAP 768            // max records per group (mean 512, +11 sigma)
#define RPT (SCAP / 256)    // records per thread staged in registers
#define MLPB 512            // blocks for out_mlp (amortize weights)
#define PREPB 256           // prep blocks inside mid_k (8 waves each)

typedef unsigned long long ull;
typedef _Float16 f16x8 __attribute__((ext_vector_type(8)));
typedef float f32x4 __attribute__((ext_vector_type(4)));

__device__ __forceinline__ float sspf(float x) {
    // fast softplus(x) - log2
    return fmaxf(x, 0.0f) + __logf(1.0f + __expf(-fabsf(x))) - LOG2C;
}

// load 8 consecutive fp32 from row-major w[f][k0..k0+7] as f16x8 (MFMA B-frag)
__device__ __forceinline__ f16x8 load_wfrag(const float* __restrict__ w, int f, int k0) {
    const float4 q0 = *(const float4*)(w + (size_t)f * NF + k0);
    const float4 q1 = *(const float4*)(w + (size_t)f * NF + k0 + 4);
    f16x8 r;
    r[0] = (_Float16)q0.x; r[1] = (_Float16)q0.y; r[2] = (_Float16)q0.z; r[3] = (_Float16)q0.w;
    r[4] = (_Float16)q1.x; r[5] = (_Float16)q1.y; r[6] = (_Float16)q1.z; r[7] = (_Float16)q1.w;
    return r;
}

__device__ __forceinline__ f16x8 load_afrag_f32(const float* __restrict__ p) {
    const float4 q0 = *(const float4*)(p);
    const float4 q1 = *(const float4*)(p + 4);
    f16x8 r;
    r[0] = (_Float16)q0.x; r[1] = (_Float16)q0.y; r[2] = (_Float16)q0.z; r[3] = (_Float16)q0.w;
    r[4] = (_Float16)q1.x; r[5] = (_Float16)q1.y; r[6] = (_Float16)q1.z; r[7] = (_Float16)q1.w;
    return r;
}

// ---------------------------------------------------------------------------
// table build (standalone; register-fat by design): 256 blocks x 256 thr.
// ---------------------------------------------------------------------------
__global__ void __launch_bounds__(256) build_tabnn_k(
    const float* __restrict__ f_w1, const float* __restrict__ f_b1,
    const float* __restrict__ f_w2, const float* __restrict__ f_b2,
    __half* __restrict__ tabnn) {
    const int tid = threadIdx.x;
    const int lane = tid & 63;
    const int wid = tid >> 6;
    float w1r[KEXP], w2r[NF];
    for (int k = 0; k < KEXP; ++k) w1r[k] = f_w1[lane * KEXP + k];
    for (int k = 0; k < NF; ++k)  w2r[k] = f_w2[lane * NF + k];
    const float b1 = f_b1[lane], b2 = f_b2[lane];
    const float delta = CUTF / (float)(KEXP - 1);
    const float coeff = -0.5f / (delta * delta);
    const float dstep = CUTF / (float)(TBL - 1);
    for (int tt = 0; tt < 16; ++tt) {
        const int t = blockIdx.x * 64 + wid * 16 + tt;
        const float d = (float)t * dstep;
        float rbfv = 0.f;
        if (lane < KEXP) {
            const float dd = d - (float)lane * delta;
            rbfv = __expf(coeff * dd * dd);
        }
        float t1 = b1;
        for (int k = 0; k < KEXP; ++k) t1 = fmaf(__shfl(rbfv, k), w1r[k], t1);
        const float sv = sspf(t1);
        float t2 = b2;
        for (int k = 0; k < NF; ++k) t2 = fmaf(__shfl(sv, k), w2r[k], t2);
        tabnn[(size_t)t * NF + lane] = __float2half(t2);
    }
}

// ---------------------------------------------------------------------------
// hist: per superchunk, histogram of dst-groups -> cnt[c][g] (coalesced)
// ---------------------------------------------------------------------------
__global__ void __launch_bounds__(1024) hist_k(const int* __restrict__ nbr_dst,
                                               int n_edges, int ngroups, int chk,
                                               unsigned* __restrict__ cnt) {
    __shared__ unsigned cnt_s[GMAX];
    const int tid = threadIdx.x;
    const int c = blockIdx.x;
    const int e0 = c * chk;
    const int e1 = min(e0 + chk, n_edges);
    const int m = max(e1 - e0, 0);
    for (int g = tid; g < ngroups; g += 1024) cnt_s[g] = 0u;
    __syncthreads();
    for (int i = tid; i < m; i += 1024)
        atomicAdd(&cnt_s[(unsigned)nbr_dst[e0 + i] >> GSH], 1u);
    __syncthreads();
    const size_t ob = (size_t)c * ngroups;
    for (int g = tid; g < ngroups; g += 1024) cnt[ob + g] = cnt_s[g];
}

// ---------------------------------------------------------------------------
// colscan: per group g, exclusive scan of cnt[c][g] along c (NSC=256, 4/lane)
// ---------------------------------------------------------------------------
__global__ void __launch_bounds__(64) colscan_k(const unsigned* __restrict__ cnt,
                                                unsigned* __restrict__ colpre,
                                                unsigned* __restrict__ tot, int ngroups) {
    const int g = blockIdx.x;
    const int lane = threadIdx.x;
    unsigned v[4];
    unsigned s = 0u;
    #pragma unroll
    for (int j = 0; j < 4; ++j) {
        v[j] = cnt[(size_t)(4 * lane + j) * ngroups + g];
        s += v[j];
    }
    unsigned run = s;
    #pragma unroll
    for (int d = 1; d < 64; d <<= 1) {
        const unsigned t = __shfl_up(run, d, 64);
        if (lane >= d) run += t;
    }
    unsigned pre = run - s;
    #pragma unroll
    for (int j = 0; j < 4; ++j) {
        colpre[(size_t)(4 * lane + j) * ngroups + g] = pre;
        pre += v[j];
    }
    if (lane == 63) tot[g] = run;
}

// ---------------------------------------------------------------------------
// base: exclusive scan over group totals -> gbase[0..ngroups]
// ---------------------------------------------------------------------------
__global__ void __launch_bounds__(64) base_k(const unsigned* __restrict__ tot,
                                             unsigned* __restrict__ gbase, int ngroups) {
    const int lane = threadIdx.x;
    unsigned carry = 0u;
    for (int base = 0; base < ngroups; base += 64) {
        const int g = base + lane;
        const unsigned v = (g < ngroups) ? tot[g] : 0u;
        unsigned run = v;
        #pragma unroll
        for (int d = 1; d < 64; d <<= 1) {
            const unsigned t = __shfl_up(run, d, 64);
            if (lane >= d) run += t;
        }
        if (g < ngroups) gbase[g] = carry + run - v;
        carry += (unsigned)__shfl((int)run, 63, 64);
    }
    if (lane == 0) gbase[ngroups] = carry;
}

// ---------------------------------------------------------------------------
// mid_k: fused [scatter | prep] — independent jobs co-executing.
//   blocks [0, NSC)           -> scatter superchunk c (512-thread stride)
//   blocks [NSC, NSC+PREPB)   -> prep MFMA tiles (8 waves/block, ~3 tiles/wave)
// rec: lo = i0<<7 ; hi = (src<<7)|dstrow(5b)
// ---------------------------------------------------------------------------
__global__ void __launch_bounds__(512) mid_k(
    // scatter
    const int* __restrict__ nbr, const float* __restrict__ dist,
    int n_edges, int ngroups, int chk,
    const unsigned* __restrict__ colpre, const unsigned* __restrict__ gbase,
    ull* __restrict__ payload,
    // prep
    const float* __restrict__ x, const float* __restrict__ w,
    const float* __restrict__ b, __half* __restrict__ h16, int n_nodes)
{
    __shared__ __align__(16) char smem[8 * 16 * 72 * 2];   // 18KB union
    const int blk = blockIdx.x;
    const int tid = threadIdx.x;
    const int lane = tid & 63;
    const int wid = tid >> 6;   // 0..7

    if (blk < NSC) {
        // ----- scatter: final globally-sorted positions -----
        unsigned* cur_s = (unsigned*)smem;   // ngroups <= GMAX = 4096 -> 16KB
        const int c = blk;
        const int e0 = c * chk;
        const int e1 = min(e0 + chk, n_edges);
        const int m = max(e1 - e0, 0);
        const size_t ob = (size_t)c * ngroups;
        for (int g = tid; g < ngroups; g += 512) cur_s[g] = gbase[g] + colpre[ob + g];
        __syncthreads();
        const float scale = (float)(TBL - 1) / CUTF;
        for (int i = tid; i < m; i += 512) {
            const int e = e0 + i;
            const unsigned dst = (unsigned)nbr[n_edges + e];
            const unsigned src = (unsigned)nbr[e];
            const float xx = dist[e] * scale + 0.5f;
            int i0 = (int)xx;
            i0 = max(0, min(i0, TBL - 1));
            const ull rec = (ull)((unsigned)i0 << 7) |
                            ((ull)((src << 7) | (dst & (GRP - 1u))) << 32);
            const unsigned pos = atomicAdd(&cur_s[dst >> GSH], 1u);
            payload[pos] = rec;
        }
    } else {
        // ----- prep (MFMA): h16 = fp16(x @ lin_w.T + lin_b), 8 waves -----
        _Float16 (*stile)[16][72] = (_Float16(*)[16][72])smem;
        const int col = lane & 15;
        const int quad = lane >> 4;
        f16x8 bw[4][2];
        float bv[4];
        #pragma unroll
        for (int t = 0; t < 4; ++t) {
            #pragma unroll
            for (int kb = 0; kb < 2; ++kb)
                bw[t][kb] = load_wfrag(w, 16 * t + col, kb * 32 + quad * 8);
            bv[t] = b[16 * t + col];
        }
        const int pb = blk - NSC;
        const int pgrid = gridDim.x - NSC;
        const int ntiles = (n_nodes + 15) >> 4;
        for (int tile = pb * 8 + wid; tile < ntiles; tile += pgrid * 8) {
            const int n0 = tile << 4;
            const int nr = min(n0 + col, n_nodes - 1);
            f16x8 a[2];
            #pragma unroll
            for (int kb = 0; kb < 2; ++kb)
                a[kb] = load_afrag_f32(x + (size_t)nr * NF + kb * 32 + quad * 8);
            f32x4 acc[4];
            #pragma unroll
            for (int t = 0; t < 4; ++t) acc[t] = (f32x4){bv[t], bv[t], bv[t], bv[t]};
            #pragma unroll
            for (int t = 0; t < 4; ++t)
                #pragma unroll
                for (int kb = 0; kb < 2; ++kb)
                    acc[t] = __builtin_amdgcn_mfma_f32_16x16x32_f16(a[kb], bw[t][kb], acc[t], 0, 0, 0);
            #pragma unroll
            for (int t = 0; t < 4; ++t)
                #pragma unroll
                for (int r = 0; r < 4; ++r)
                    stile[wid][quad * 4 + r][16 * t + col] = (_Float16)acc[t][r];
            __threadfence_block();
            #pragma unroll
            for (int it = 0; it < 2; ++it) {
                const int chunk = it * 64 + lane;
                const int row = chunk >> 3;
                const int off = (chunk & 7) * 8;
                const int n = n0 + row;
                if (n < n_nodes)
                    *(uint4*)(h16 + (size_t)n * NF + off) = *(const uint4*)&stile[wid][row][off];
            }
            __threadfence_block();
        }
    }
}

// ---------------------------------------------------------------------------
// agg: block = 32-node group. Register-staged single read + count, row-sort
// into LDS, then pure gather-accumulate with 16-deep load pipelining.
// ---------------------------------------------------------------------------
__global__ void __launch_bounds__(256) agg_k(
    const ull* __restrict__ payload, const unsigned* __restrict__ gbase,
    const __half* __restrict__ h16, const __half* __restrict__ tabnn,
    float* __restrict__ agg, int n_nodes)
{
    __shared__ ull sorted_s[SCAP];
    __shared__ unsigned cnt_s[GRP];
    __shared__ unsigned base_s[GRP];
    __shared__ unsigned cur_s[GRP];
    const int tid = threadIdx.x;
    const int lane = tid & 63;
    const int wid = tid >> 6;   // 0..3
    const int g = blockIdx.x;
    const unsigned beg = gbase[g];
    const unsigned end = gbase[g + 1];
    const unsigned tot = min(end - beg, (unsigned)SCAP);

    if (tid < GRP) cnt_s[tid] = 0u;
    __syncthreads();
    // Phase A: stage records in registers (coalesced), count rows
    ull rec[RPT];
    #pragma unroll
    for (int k = 0; k < RPT; ++k) {
        const unsigned i = (unsigned)(k * 256) + tid;
        rec[k] = 0ull;
        if (i < tot) {
            rec[k] = payload[beg + i];
            atomicAdd(&cnt_s[(unsigned)(rec[k] >> 32) & (GRP - 1u)], 1u);
        }
    }
    __syncthreads();
    // exclusive scan over GRP row counts (lanes 0..GRP-1 of wave 0)
    if (tid < GRP) {
        const unsigned c = cnt_s[tid];
        unsigned run = c;
        #pragma unroll
        for (int d = 1; d < GRP; d <<= 1) {
            const unsigned t = __shfl_up(run, d, 64);
            if (tid >= d) run += t;
        }
        base_s[tid] = run - c;
        cur_s[tid]  = run - c;
    }
    __syncthreads();
    // Phase B: place by row (registers -> LDS)
    #pragma unroll
    for (int k = 0; k < RPT; ++k) {
        const unsigned i = (unsigned)(k * 256) + tid;
        if (i < tot) {
            const unsigned pos = atomicAdd(&cur_s[(unsigned)(rec[k] >> 32) & (GRP - 1u)], 1u);
            sorted_s[pos] = rec[k];
        }
    }
    __syncthreads();
    // Phase C: gather-accumulate; one coalesced store per row
    const char* tabB = (const char*)tabnn + (lane << 1);
    const char* hB   = (const char*)h16 + (lane << 1);
    auto ev = [&](ull r) -> float {
        const unsigned lo = (unsigned)r;          // tab row byte offset
        const unsigned hi = (unsigned)(r >> 32);
        const float tv = __half2float(*(const __half*)(tabB + lo));
        const float hv = __half2float(*(const __half*)(hB + (hi & 0xFFFFFF80u)));
        return tv * hv;
    };
    const int n0 = g * GRP;
    for (int rr = 0; rr < GRP / 4; ++rr) {
        const int r = wid * (GRP / 4) + rr;
        unsigned i = base_s[r];
        const unsigned e = cur_s[r];
        float acc0 = 0.f, acc1 = 0.f;
        for (; i + 16u <= e; i += 16u) {
            ull rv[16];
            #pragma unroll
            for (int j = 0; j < 16; ++j) rv[j] = sorted_s[i + j];
            float p[16];
            #pragma unroll
            for (int j = 0; j < 16; ++j) p[j] = ev(rv[j]);
            acc0 += ((p[0] + p[1]) + (p[2] + p[3])) + ((p[4] + p[5]) + (p[6] + p[7]));
            acc1 += ((p[8] + p[9]) + (p[10] + p[11])) + ((p[12] + p[13]) + (p[14] + p[15]));
        }
        for (; i + 4u <= e; i += 4u) {
            const ull r0 = sorted_s[i];
            const ull r1 = sorted_s[i + 1];
            const ull r2 = sorted_s[i + 2];
            const ull r3 = sorted_s[i + 3];
            acc0 += ev(r0) + ev(r1);
            acc1 += ev(r2) + ev(r3);
        }
        for (; i < e; ++i) acc0 += ev(sorted_s[i]);
        const int n = n0 + r;
        if (n < n_nodes) agg[(size_t)n * NF + lane] = acc0 + acc1;
    }
}

// ---------------------------------------------------------------------------
// overflow fixup: groups with >SCAP records (normally zero work)
// ---------------------------------------------------------------------------
__global__ void __launch_bounds__(64) oflow2_k(const ull* __restrict__ payload,
                                               const unsigned* __restrict__ gbase,
                                               const __half* __restrict__ h16,
                                               const __half* __restrict__ tabnn,
                                               float* __restrict__ agg) {
    const int g = blockIdx.x;
    const unsigned beg = gbase[g];
    const unsigned end = gbase[g + 1];
    if (end - beg <= (unsigned)SCAP) return;
    const int lane = threadIdx.x;
    const char* tabB = (const char*)tabnn + (lane << 1);
    const char* hB   = (const char*)h16 + (lane << 1);
    for (unsigned i = beg + SCAP; i < end; ++i) {
        const ull rec = payload[i];
        const unsigned lo = (unsigned)rec;
        const unsigned hi = (unsigned)(rec >> 32);
        const float tv = __half2float(*(const __half*)(tabB + lo));
        const float hv = __half2float(*(const __half*)(hB + (hi & 0xFFFFFF80u)));
        const unsigned row = (unsigned)g * GRP + (hi & (GRP - 1u));
        atomicAdd(agg + (size_t)row * NF + lane, tv * hv);
    }
}

// ---------------------------------------------------------------------------
// fallback edge kernel (direct atomic scatter-add) — used only if ws too small
// ---------------------------------------------------------------------------
__global__ void edge_k(const int* __restrict__ nbr, const float* __restrict__ dist,
                       const __half* __restrict__ h16, const __half* __restrict__ tabnn,
                       float* __restrict__ agg, int n_edges) {
    const int tid = threadIdx.x;
    const int lane = tid & 63;
    const int nwaves = (gridDim.x * blockDim.x) >> 6;
    const int gw = (blockIdx.x * blockDim.x + tid) >> 6;
    const float scale = (float)(TBL - 1) / CUTF;
    const int nbatch = n_edges >> 6;
    for (int bb = gw; bb < nbatch; bb += nwaves) {
        const int e0 = bb << 6;
        int src = nbr[e0 + lane];
        int dst = nbr[n_edges + e0 + lane];
        float d = dist[e0 + lane];
        float xx = d * scale + 0.5f;
        int i0 = (int)xx;
        i0 = max(0, min(i0, TBL - 1));
        #pragma unroll 4
        for (int j = 0; j < 64; ++j) {
            const int sj = __shfl(src, j);
            const int dj = __shfl(dst, j);
            const int ij = __shfl(i0, j);
            const float tv = __half2float(tabnn[(size_t)ij * NF + lane]);
            const float hv = __half2float(h16[(size_t)sj * NF + lane]);
            atomicAdd(agg + (size_t)dj * NF + lane, tv * hv);
        }
    }
    if (gw == 0) {
        for (int e = nbatch << 6; e < n_edges; ++e) {
            const int sj = nbr[e];
            const int dj = nbr[n_edges + e];
            const float d = dist[e];
            float xx = d * scale + 0.5f;
            int ij = (int)xx;
            ij = max(0, min(ij, TBL - 1));
            const float tv = __half2float(tabnn[(size_t)ij * NF + lane]);
            const float hv = __half2float(h16[(size_t)sj * NF + lane]);
            atomicAdd(agg + (size_t)dj * NF + lane, tv * hv);
        }
    }
}

// ---------------------------------------------------------------------------
// out_mlp (MFMA): out = ssp(agg@W1^T+b1)@W2^T+b2. Wave per 16-node tile,
// ~3 tiles per wave (MLPB blocks) to amortize the weight preload.
// ---------------------------------------------------------------------------
__global__ void __launch_bounds__(256) out_mlp_k(const float* __restrict__ agg,
                                                 const float* __restrict__ w1,
                                                 const float* __restrict__ b1,
                                                 const float* __restrict__ w2,
                                                 const float* __restrict__ b2,
                                                 float* __restrict__ out, int n_nodes) {
    __shared__ _Float16 stile[4][16][72];
    const int tid = threadIdx.x;
    const int lane = tid & 63;
    const int wid = tid >> 6;
    const int col = lane & 15;
    const int quad = lane >> 4;

    f16x8 bw1[4][2], bw2[4][2];
    float b1v[4], b2v[4];
    #pragma unroll
    for (int t = 0; t < 4; ++t) {
        #pragma unroll
        for (int kb = 0; kb < 2; ++kb) {
            bw1[t][kb] = load_wfrag(w1, 16 * t + col, kb * 32 + quad * 8);
            bw2[t][kb] = load_wfrag(w2, 16 * t + col, kb * 32 + quad * 8);
        }
        b1v[t] = b1[16 * t + col];
        b2v[t] = b2[16 * t + col];
    }

    const int ntiles = (n_nodes + 15) >> 4;
    for (int tile = blockIdx.x * 4 + wid; tile < ntiles; tile += gridDim.x * 4) {
        const int n0 = tile << 4;
        const int nr = min(n0 + col, n_nodes - 1);
        f16x8 a[2];
        #pragma unroll
        for (int kb = 0; kb < 2; ++kb)
            a[kb] = load_afrag_f32(agg + (size_t)nr * NF + kb * 32 + quad * 8);
        f32x4 acc[4];
        #pragma unroll
        for (int t = 0; t < 4; ++t) acc[t] = (f32x4){b1v[t], b1v[t], b1v[t], b1v[t]};
        #pragma unroll
        for (int t = 0; t < 4; ++t)
            #pragma unroll
            for (int kb = 0; kb < 2; ++kb)
                acc[t] = __builtin_amdgcn_mfma_f32_16x16x32_f16(a[kb], bw1[t][kb], acc[t], 0, 0, 0);
        #pragma unroll
        for (int t = 0; t < 4; ++t)
            #pragma unroll
            for (int r = 0; r < 4; ++r)
                stile[wid][quad * 4 + r][16 * t + col] = (_Float16)sspf(acc[t][r]);
        __threadfence_block();
        f16x8 a2[2];
        #pragma unroll
        for (int kb = 0; kb < 2; ++kb)
            a2[kb] = *(const f16x8*)&stile[wid][col][kb * 32 + quad * 8];
        f32x4 acc2[4];
        #pragma unroll
        for (int t = 0; t < 4; ++t) acc2[t] = (f32x4){b2v[t], b2v[t], b2v[t], b2v[t]};
        #pragma unroll
        for (int t = 0; t < 4; ++t)
            #pragma unroll
            for (int kb = 0; kb < 2; ++kb)
                acc2[t] = __builtin_amdgcn_mfma_f32_16x16x32_f16(a2[kb], bw2[t][kb], acc2[t], 0, 0, 0);
        #pragma unroll
        for (int t = 0; t < 4; ++t)
            #pragma unroll
            for (int r = 0; r < 4; ++r) {
                const int n = n0 + quad * 4 + r;
                if (n < n_nodes) out[(size_t)n * NF + 16 * t + col] = acc2[t][r];
            }
        __threadfence_block();
    }
}

extern "C" void kernel_launch(void* const* d_in, const int* in_sizes, int n_in,
                              void* d_out, int out_size, void* d_ws, size_t ws_size,
                              hipStream_t stream) {
    const int*   nbr   = (const int*)d_in[0];
    const float* dist  = (const float*)d_in[1];
    const float* x     = (const float*)d_in[2];
    const float* lin_w = (const float*)d_in[3];
    const float* lin_b = (const float*)d_in[4];
    const float* f_w1  = (const float*)d_in[5];
    const float* f_b1  = (const float*)d_in[6];
    const float* f_w2  = (const float*)d_in[7];
    const float* f_b2  = (const float*)d_in[8];
    const float* m_w1  = (const float*)d_in[9];
    const float* m_b1  = (const float*)d_in[10];
    const float* m_w2  = (const float*)d_in[11];
    const float* m_b2  = (const float*)d_in[12];

    const int n_edges = in_sizes[1];
    const int n_nodes = in_sizes[2] / NF;
    const int ngroups = (n_nodes + GRP - 1) / GRP;
    const int chk     = (n_edges + NSC - 1) / NSC;
    const int ntiles  = (n_nodes + 15) / 16;
    const int mlp_blk = (ntiles + 3) / 4;
    const int tile_blk = mlp_blk < MLPB ? mlp_blk : MLPB;
    const int prep_blk8 = (ntiles + 7) / 8 < PREPB ? (ntiles + 7) / 8 : PREPB;

    float* out = (float*)d_out;
    float* agg = out;   // agg lives in d_out; out_mlp runs in place

    // workspace: h16 | tabnn | cnt | colpre | tot | gbase | payload
    char* ws = (char*)d_ws;
    size_t off = 0;
    auto alloc = [&](size_t bytes) { char* p = ws + off; off = (off + bytes + 255) & ~(size_t)255; return p; };
    __half*   h16     = (__half*)alloc((size_t)n_nodes * NF * sizeof(__half));
    __half*   tabnn   = (__half*)alloc((size_t)TBL * NF * sizeof(__half));
    unsigned* cnt     = (unsigned*)alloc((size_t)NSC * ngroups * sizeof(unsigned));
    unsigned* colpre  = (unsigned*)alloc((size_t)NSC * ngroups * sizeof(unsigned));
    unsigned* tot     = (unsigned*)alloc((size_t)ngroups * sizeof(unsigned));
    unsigned* gbase   = (unsigned*)alloc((size_t)(ngroups + 1) * sizeof(unsigned));
    ull*      payload = (ull*)alloc((size_t)NSC * chk * sizeof(ull));
    const bool sort_path = (off <= ws_size) && (ngroups <= GMAX) && (n_nodes <= (1 << 17));

    build_tabnn_k<<<TBL / 64, 256, 0, stream>>>(f_w1, f_b1, f_w2, f_b2, tabnn);

    if (sort_path) {
        hist_k<<<NSC, 1024, 0, stream>>>(nbr + n_edges, n_edges, ngroups, chk, cnt);
        colscan_k<<<ngroups, 64, 0, stream>>>(cnt, colpre, tot, ngroups);
        base_k<<<1, 64, 0, stream>>>(tot, gbase, ngroups);
        // fused mid: scatter + prep co-execute (independent jobs)
        mid_k<<<NSC + prep_blk8, 512, 0, stream>>>(
            nbr, dist, n_edges, ngroups, chk, colpre, gbase, payload,
            x, lin_w, lin_b, h16, n_nodes);
        agg_k<<<ngroups, 256, 0, stream>>>(payload, gbase, h16, tabnn, agg, n_nodes);
        oflow2_k<<<ngroups, 64, 0, stream>>>(payload, gbase, h16, tabnn, agg);
    } else {
        // fallback: prep via mid_k's prep-only blocks, then atomic edge path
        mid_k<<<prep_blk8, 512, 0, stream>>>(
            nbr, dist, 0, ngroups, 0, colpre, gbase, payload,  // scatter part skipped (blk<NSC does nothing with n_edges=0)
            x, lin_w, lin_b, h16, n_nodes);
        hipMemsetAsync(agg, 0, (size_t)n_nodes * NF * sizeof(float), stream);
        edge_k<<<2048, 256, 0, stream>>>(nbr, dist, h16, tabnn, agg, n_edges);
    }
    out_mlp_k<<<tile_blk, 256, 0, stream>>>(agg, m_w1, m_b1, m_w2, m_b2, out, n_nodes);
}